// Round 6
// baseline (168.424 us; speedup 1.0000x reference)
//
#include <hip/hip_runtime.h>
#include <hip/hip_bf16.h>

// LightningAttention MI355X — round 14.
// = R13 (best: 160.5us) with ONE instrumentation change: k_qkv launched as TWO
//   512-block dispatches (row-offset param). Each half ~29.5us < k_zout (if k_zout
//   >= 30us), so next round's top-5 reveals k_zout's counters — the largest
//   unattributed term (total - k_qkv - prep/mprep - gaps ≈ 40-95us uncertainty).
//   If k_qkv halves still top the list, k_zout < 29.5us and the hole is launch
//   overhead -> fuse kernels next.
// B=8 T=8192 DM=128 H=8 Dh=16. Split-bf16 (hi+lo) on all MFMA surfaces except q' (bf16).

typedef __attribute__((ext_vector_type(8))) short short8;   // 8 bf16 (MFMA A/B frag)
typedef __attribute__((ext_vector_type(4))) float floatx4;  // MFMA C/D frag

#define DEV __device__ __forceinline__
#define MFMA __builtin_amdgcn_mfma_f32_16x16x32_bf16

#define XPAD 136   // x-tile row stride in shorts. 136 -> LDS 39424B -> 4 blocks/CU. Do not grow.

DEV unsigned short bfh(float f) {
  unsigned int x = __float_as_uint(f);
  x += 0x7fffu + ((x >> 16) & 1u);     // RNE
  return (unsigned short)(x >> 16);
}
DEV float bfdec(unsigned short u) { return __uint_as_float(((unsigned int)u) << 16); }
DEV void splitf(float f, unsigned short& h, unsigned short& l) {
  h = bfh(f);
  l = bfh(f - bfdec(h));
}
DEV void split8(const float* p, short8& h8, short8& l8) {
  float4 a = *(const float4*)p;
  float4 b = *(const float4*)(p + 4);
  float v[8] = {a.x, a.y, a.z, a.w, b.x, b.y, b.z, b.w};
  union { short8 s; unsigned short u[8]; } H, L;
#pragma unroll
  for (int i = 0; i < 8; ++i) splitf(v[i], H.u[i], L.u[i]);
  h8 = H.s; l8 = L.s;
}

// Register transpose (verified R5-R7): C-layout tile val(n=lane16, m=mt*16+quad*4+r),
// rows m0/m1 -> split frag F[lane16][k=quad*8+j] over the 32-wide m-window.
DEV void xpose_frag(floatx4 m0, floatx4 m1, int lane16, int quad,
                    short8& hi, short8& lo) {
  union { short8 s; unsigned short u[8]; } H, L;
#pragma unroll
  for (int j = 0; j < 8; ++j) {
    int srcLane = lane16 + (((quad & 1) * 2 + (j >> 2)) << 4);
    float vA = __shfl(m0[j & 3], srcLane, 64);
    float vB = __shfl(m1[j & 3], srcLane, 64);
    float v = (quad < 2) ? vA : vB;
    splitf(v, H.u[j], L.u[j]);
  }
  hi = H.s; lo = L.s;
}

// async 16B global->LDS (per-lane gsrc; LDS dest must be wave-uniform base + lane*16)
DEV void async16(const void* g, void* l) {
  __builtin_amdgcn_global_load_lds(
      (const __attribute__((address_space(1))) unsigned int*)g,
      (__attribute__((address_space(3))) unsigned int*)l, 16, 0, 0);
}

// ---------------- k_prep: Wq/Wk/Wv split-transpose + zero ctx/ksum ----------------
__global__ void k_prep(const float* __restrict__ Wq, const float* __restrict__ Wk,
                       const float* __restrict__ Wv,
                       unsigned short* __restrict__ WTh, unsigned short* __restrict__ WTl,
                       float* __restrict__ ctxz) {
  int gid = blockIdx.x * 256 + threadIdx.x;
  if (gid < 6144) {               // 3 mats x 128 n x 16 k-groups of 8
    int mat = gid >> 11, r = gid & 2047, n = r >> 4, k0 = (r & 15) * 8;
    const float* W = (mat == 0) ? Wq : (mat == 1) ? Wk : Wv;
    union { uint4 q; unsigned short u[8]; } oh, ol;
#pragma unroll
    for (int i = 0; i < 8; ++i) splitf(W[(size_t)(k0 + i) * 128 + n], oh.u[i], ol.u[i]);
    *(uint4*)&WTh[mat * 16384 + n * 128 + k0] = oh.q;
    *(uint4*)&WTl[mat * 16384 + n * 128 + k0] = ol.q;
  } else if (gid < 6144 + 17408) {
    ctxz[gid - 6144] = 0.0f;      // ctx (16384) + ksum (1024)
  }
}

// ---------------- kernel 1: qkv GEMM + rope/elu + q'/ksum/ctx. 512 thr, wave=1 head ----------------
// Launched twice with blk0 = {0, 512} (instrumentation split; see header comment).
__global__ __launch_bounds__(512) void k_qkv(
    const float* __restrict__ x,
    const unsigned short* __restrict__ WTh, const unsigned short* __restrict__ WTl,
    const float* __restrict__ bq, const float* __restrict__ bk, const float* __restrict__ bv,
    float* __restrict__ ctx, float* __restrict__ ksum,
    unsigned short* __restrict__ qws, int blk0) {
  __shared__ unsigned short xh[64 * XPAD], xl[64 * XPAD];   // pre-split x tile [row][k]
  __shared__ float rc[64][9], rs[64][9];
  const int tid = threadIdx.x;
  const int row0 = (blockIdx.x + blk0) * 64;
  const int b = row0 >> 13;
  const int t0 = row0 & 8191;

  {  // rope table: 512 threads -> 64 rows x 8 j
    int r = tid >> 3, j = tid & 7;
    float invf = 1.0f / powf(10000.0f, (float)j * 0.125f);
    float s, c;
    sincosf((float)(t0 + r) * invf, &s, &c);
    rc[r][j] = c; rs[r][j] = s;
  }
  {  // stage x, split ONCE per element
    int r = tid >> 3, cg = (tid & 7) * 16;
    const float* xp = x + (size_t)(row0 + r) * 128 + cg;
    short8 h0, l0, h1, l1;
    split8(xp, h0, l0);
    split8(xp + 8, h1, l1);
    *(short8*)&xh[r * XPAD + cg] = h0;
    *(short8*)&xh[r * XPAD + cg + 8] = h1;
    *(short8*)&xl[r * XPAD + cg] = l0;
    *(short8*)&xl[r * XPAD + cg + 8] = l1;
  }
  __syncthreads();                 // only barrier

  const int l = tid & 63, w = tid >> 6;       // wave w owns head w
  const int lane16 = l & 15, quad = l >> 4;

  floatx4 acc[3][4];               // [mat: q,k,v][mt]  = 48 AGPRs
#pragma unroll
  for (int i = 0; i < 3; ++i)
#pragma unroll
    for (int j = 0; j < 4; ++j) acc[i][j] = (floatx4){0.f, 0.f, 0.f, 0.f};

  // weight base offsets per mat (ks advances by +32 shorts)
  size_t wbase[3];
#pragma unroll
  for (int mat = 0; mat < 3; ++mat)
    wbase[mat] = (size_t)mat * 16384 + (size_t)(w * 16 + lane16) * 128 + quad * 8;

  // double-buffered weight frags: prefetch ks+1 while computing ks
  short8 wh[2][3], wl[2][3];
#pragma unroll
  for (int mat = 0; mat < 3; ++mat) {
    wh[0][mat] = *(const short8*)(WTh + wbase[mat]);
    wl[0][mat] = *(const short8*)(WTl + wbase[mat]);
  }

#pragma unroll
  for (int ks = 0; ks < 4; ++ks) {
    const int cur = ks & 1, nxt = cur ^ 1;
    if (ks < 3) {
#pragma unroll
      for (int mat = 0; mat < 3; ++mat) {
        wh[nxt][mat] = *(const short8*)(WTh + wbase[mat] + (ks + 1) * 32);
        wl[nxt][mat] = *(const short8*)(WTl + wbase[mat] + (ks + 1) * 32);
      }
    }
    short8 afh[4], afl[4];
#pragma unroll
    for (int mt = 0; mt < 4; ++mt) {
      int off = (mt * 16 + lane16) * XPAD + ks * 32 + quad * 8;
      afh[mt] = *(const short8*)&xh[off];
      afl[mt] = *(const short8*)&xl[off];
    }
#pragma unroll
    for (int mat = 0; mat < 3; ++mat) {
#pragma unroll
      for (int mt = 0; mt < 4; ++mt) {
        acc[mat][mt] = MFMA(afh[mt], wh[cur][mat], acc[mat][mt], 0, 0, 0);
        acc[mat][mt] = MFMA(afl[mt], wh[cur][mat], acc[mat][mt], 0, 0, 0);
        acc[mat][mt] = MFMA(afh[mt], wl[cur][mat], acc[mat][mt], 0, 0, 0);
      }
    }
  }

  // bias (lane16 = col within head)
  {
    int col = w * 16 + lane16;
    float bias[3] = {bq[col], bk[col], bv[col]};
#pragma unroll
    for (int mat = 0; mat < 3; ++mat)
#pragma unroll
      for (int mt = 0; mt < 4; ++mt)
#pragma unroll
        for (int r = 0; r < 4; ++r) acc[mat][mt][r] += bias[mat];
  }

  // rope + elu+1 on q (mat 0) and k (mat 1). lane16 = d; t = mt*16 + quad*4 + r.
  {
    const int d = lane16, j = d & 7;
#pragma unroll
    for (int mt = 0; mt < 4; ++mt) {
      float cc[4], ss[4];
#pragma unroll
      for (int r = 0; r < 4; ++r) {
        int tl = mt * 16 + quad * 4 + r;
        cc[r] = rc[tl][j]; ss[r] = rs[tl][j];
      }
#pragma unroll
      for (int mat = 0; mat < 2; ++mat) {
#pragma unroll
        for (int r = 0; r < 4; ++r) {
          float v = acc[mat][mt][r];
          float p = __shfl_xor(v, 8);          // pair (d, d+8)
          float nv = (d < 8) ? (v * cc[r] - p * ss[r]) : (p * ss[r] + v * cc[r]);
          acc[mat][mt][r] = (nv > 0.f) ? (nv + 1.f) : __expf(nv);
        }
      }
    }
  }

  // ksum[h=w][d] from k
  {
    float s = 0.f;
#pragma unroll
    for (int mt = 0; mt < 4; ++mt)
#pragma unroll
      for (int r = 0; r < 4; ++r) s += acc[1][mt][r];
    s += __shfl_xor(s, 16);
    s += __shfl_xor(s, 32);
    if (l < 16) atomicAdd(&ksum[(b * 8 + w) * 16 + lane16], s);
  }

  // q' -> ws bf16 [t][128]
#pragma unroll
  for (int mt = 0; mt < 4; ++mt)
#pragma unroll
    for (int r = 0; r < 4; ++r)
      qws[(size_t)(row0 + mt * 16 + quad * 4 + r) * 128 + w * 16 + lane16] =
          bfh(acc[0][mt][r]);

  // ctx[h=w] += K^T V via register transposes (2 t-windows of 32)
  {
    floatx4 c = (floatx4){0.f, 0.f, 0.f, 0.f};
#pragma unroll
    for (int ks2 = 0; ks2 < 2; ++ks2) {
      short8 kh, kl, vh, vl;
      xpose_frag(acc[1][ks2 * 2], acc[1][ks2 * 2 + 1], lane16, quad, kh, kl);
      xpose_frag(acc[2][ks2 * 2], acc[2][ks2 * 2 + 1], lane16, quad, vh, vl);
      c = MFMA(kh, vh, c, 0, 0, 0);
      c = MFMA(kl, vh, c, 0, 0, 0);
      c = MFMA(kh, vl, c, 0, 0, 0);
    }
#pragma unroll
    for (int r = 0; r < 4; ++r)
      atomicAdd(&ctx[((size_t)(b * 8 + w) * 16 + quad * 4 + r) * 16 + lane16], c[r]);
  }
}

// ---------------- k_mprep: M = C_h @ Wo_h (fp32) -> frag-major permuted split-bf16 ----------------
// Consumer frag (nt,ks), lane l reads 16B at group ((nt*4+ks)*64 + l); element j = qc ks*32+(l>>4)*8+j.
__global__ void k_mprep(const float* __restrict__ Wo, const float* __restrict__ ctx,
                        unsigned short* __restrict__ MTh, unsigned short* __restrict__ MTl) {
  int gid = blockIdx.x * 256 + threadIdx.x;   // 64 blocks: 8 b x 128 oc x 16 qc-groups
  int b = gid >> 11, r = gid & 2047, oc = r >> 4, qcg = r & 15;
  int h = qcg >> 1, d0 = (qcg & 1) * 8;
  const float* C = ctx + (size_t)(b * 8 + h) * 256;   // [d][e]
  float m[8] = {0.f, 0.f, 0.f, 0.f, 0.f, 0.f, 0.f, 0.f};
#pragma unroll 4
  for (int e = 0; e < 16; ++e) {
    float wv = Wo[(size_t)(h * 16 + e) * 128 + oc];
#pragma unroll
    for (int i = 0; i < 8; ++i) m[i] += C[(d0 + i) * 16 + e] * wv;
  }
  union { uint4 q; unsigned short u[8]; } oh, ol;
#pragma unroll
  for (int i = 0; i < 8; ++i) splitf(m[i], oh.u[i], ol.u[i]);
  // permuted group index: nt=oc>>4, ks=qcg>>2, l = (qcg&3)*16 + (oc&15)
  int grp = (((oc >> 4) * 4 + (qcg >> 2)) * 64) + (qcg & 3) * 16 + (oc & 15);
  *(uint4*)&MTh[(size_t)b * 16384 + grp * 8] = oh.q;
  *(uint4*)&MTl[(size_t)b * 16384 + grp * 8] = ol.q;
}

// ---------------- kernel 2: out = (z .* q') @ M + bo. M staged in LDS. ----------------
// 512 blocks x 512 thr (8 waves); block = 128 rows, wave w = one 16-row m-tile.
__global__ __launch_bounds__(512) void k_zout(
    const unsigned short* __restrict__ qws,
    const unsigned short* __restrict__ MTh, const unsigned short* __restrict__ MTl,
    const float* __restrict__ bo, const float* __restrict__ ksum,
    float* __restrict__ out) {
  __shared__ __align__(16) unsigned short mh[16384], ml[16384];  // 32KB + 32KB, frag-major
  __shared__ float ksumS[128], boS[128];
  const int tid = threadIdx.x;
  const int row0 = blockIdx.x * 128;
  const int b = row0 >> 13;
  const int l = tid & 63, w = tid >> 6;
  const int lane16 = l & 15, quad = l >> 4;

  {  // async-stage M (this batch's 64KB) into LDS: wave w copies chunks (i*8+w)*1KB
    const char* gh = (const char*)(MTh + (size_t)b * 16384);
    const char* gl = (const char*)(MTl + (size_t)b * 16384);
#pragma unroll
    for (int i = 0; i < 4; ++i) {
      int off = (i * 8 + w) * 1024 + l * 16;
      async16(gh + off, (char*)mh + off);
      async16(gl + off, (char*)ml + off);
    }
  }
  if (tid < 128) ksumS[tid] = ksum[b * 128 + tid];
  else if (tid < 256) boS[tid - 128] = bo[tid - 128];
  __syncthreads();                 // drains async staging too

  // A-frags: q' direct from ws (already frag-layout), z in-reg, scale+split
  short8 ah[4], al[4];
  {
    int trow = row0 + w * 16 + lane16;      // lane16 = t within the wave's 16-row strip
#pragma unroll
    for (int ks = 0; ks < 4; ++ks) {
      union { short8 s8; unsigned short u[8]; } qq;
      qq.s8 = *(const short8*)&qws[(size_t)trow * 128 + ks * 32 + quad * 8];
      int kb = ks * 32 + quad * 8;
      float s = 0.f;
#pragma unroll
      for (int j = 0; j < 8; ++j) s += bfdec(qq.u[j]) * ksumS[kb + j];
      s += __shfl_xor(s, 16);        // combine the two 8-halves of the head
      float z = 1.0f / (s + 1e-6f);
      union { short8 s8; unsigned short u[8]; } H, L;
#pragma unroll
      for (int j = 0; j < 8; ++j) splitf(bfdec(qq.u[j]) * z, H.u[j], L.u[j]);
      ah[ks] = H.s8;
      al[ks] = L.s8;
    }
  }

  floatx4 oacc[8];
#pragma unroll
  for (int i = 0; i < 8; ++i) oacc[i] = (floatx4){0.f, 0.f, 0.f, 0.f};

#pragma unroll
  for (int nt = 0; nt < 8; ++nt) {
#pragma unroll
    for (int ks = 0; ks < 4; ++ks) {
      int moff = ((nt * 4 + ks) * 64 + l) * 8;        // frag-major: lane-contiguous 16B
      short8 wbh = *(const short8*)&mh[moff];
      short8 wbl = *(const short8*)&ml[moff];
      oacc[nt] = MFMA(ah[ks], wbh, oacc[nt], 0, 0, 0);
      oacc[nt] = MFMA(al[ks], wbh, oacc[nt], 0, 0, 0);
      oacc[nt] = MFMA(ah[ks], wbl, oacc[nt], 0, 0, 0);
    }
  }

#pragma unroll
  for (int nt = 0; nt < 8; ++nt) {
    int oc = nt * 16 + lane16;
    float bb = boS[oc];
#pragma unroll
    for (int r = 0; r < 4; ++r) {
      int t = row0 + w * 16 + quad * 4 + r;
      out[(size_t)t * 128 + oc] = oacc[nt][r] + bb;
    }
  }
}

extern "C" void kernel_launch(void* const* d_in, const int* in_sizes, int n_in,
                              void* d_out, int out_size, void* d_ws, size_t ws_size,
                              hipStream_t stream) {
  const float* x  = (const float*)d_in[0];
  const float* Wq = (const float*)d_in[1];
  const float* bq = (const float*)d_in[2];
  const float* Wk = (const float*)d_in[3];
  const float* bk = (const float*)d_in[4];
  const float* Wv = (const float*)d_in[5];
  const float* bv = (const float*)d_in[6];
  const float* Wo = (const float*)d_in[7];
  const float* bo = (const float*)d_in[8];
  float* out = (float*)d_out;

  // ws: qws 16.78MB | WTh 96KB | WTl 96KB | ctx 64KB | ksum 4KB | MTh 256KB | MTl 256KB
  unsigned short* qws = (unsigned short*)d_ws;         // 65536*128 shorts
  unsigned short* WTh = qws + 8388608;                 // 3 x 16384
  unsigned short* WTl = WTh + 49152;
  float* ctx  = (float*)(WTl + 49152);                 // 16384 f
  float* ksum = ctx + 16384;                           // 1024 f
  unsigned short* MTh = (unsigned short*)(ksum + 1024);  // 8 x 16384
  unsigned short* MTl = MTh + 131072;

  k_prep<<<92, 256, 0, stream>>>(Wq, Wk, Wv, WTh, WTl, ctx);
  k_qkv<<<512, 512, 0, stream>>>(x, WTh, WTl, bq, bk, bv, ctx, ksum, qws, 0);
  k_qkv<<<512, 512, 0, stream>>>(x, WTh, WTl, bq, bk, bv, ctx, ksum, qws, 512);
  k_mprep<<<64, 256, 0, stream>>>(Wo, ctx, MTh, MTl);
  k_zout<<<512, 512, 0, stream>>>(qws, MTh, MTl, bo, ksum, out);
}

// Round 7
// 166.677 us; speedup vs baseline: 1.0105x; 1.0105x over previous
//
#include <hip/hip_runtime.h>
#include <hip/hip_bf16.h>

// LightningAttention MI355X — round 15.
// Discovery (R14): dur_us includes a ~42.6us harness 256MB workspace re-poison
//   (fillBufferAligned @ 6.3TB/s) — fixed tax. Actionable budget ~115us:
//   qkv 58.5 | zout 30-41 (bounded by top-5 absence + budget) | prep/mprep ~4 | gaps ~10.
// Changes vs R13:
//  (1) k_qkv merged back to 1024 blocks (split cost +8us).
//  (2) k_qkv ctx transpose: 128 ds_bpermute + 128 cndmask (serial per-j chains; the
//      layout-invariant 2.92M bank conflicts) -> LDS transpose through dead xh/xl
//      (pad-17 f32 scratch, 32 ds_write + 32 ds_read, algebraically identical frag
//      t = win*32 + quad*8 + j). One extra __syncthreads for scratch reuse.
//      __launch_bounds__(512,4) pins regs <=128 (4 waves/SIMD cliff).
//  (3) k_zout: A-frag prologue hoisted ABOVE the staging barrier (ksum read from
//      global, broadcast L2) — prologue hides under the 64KB global_load_lds drain.
// B=8 T=8192 DM=128 H=8 Dh=16. Split-bf16 (hi+lo) on all MFMA surfaces except q' (bf16).

typedef __attribute__((ext_vector_type(8))) short short8;   // 8 bf16 (MFMA A/B frag)
typedef __attribute__((ext_vector_type(4))) float floatx4;  // MFMA C/D frag

#define DEV __device__ __forceinline__
#define MFMA __builtin_amdgcn_mfma_f32_16x16x32_bf16

#define XPAD 136   // x-tile row stride in shorts. 136 -> LDS 39424B. Do not grow.

DEV unsigned short bfh(float f) {
  unsigned int x = __float_as_uint(f);
  x += 0x7fffu + ((x >> 16) & 1u);     // RNE
  return (unsigned short)(x >> 16);
}
DEV float bfdec(unsigned short u) { return __uint_as_float(((unsigned int)u) << 16); }
DEV void splitf(float f, unsigned short& h, unsigned short& l) {
  h = bfh(f);
  l = bfh(f - bfdec(h));
}
DEV void split8(const float* p, short8& h8, short8& l8) {
  float4 a = *(const float4*)p;
  float4 b = *(const float4*)(p + 4);
  float v[8] = {a.x, a.y, a.z, a.w, b.x, b.y, b.z, b.w};
  union { short8 s; unsigned short u[8]; } H, L;
#pragma unroll
  for (int i = 0; i < 8; ++i) splitf(v[i], H.u[i], L.u[i]);
  h8 = H.s; l8 = L.s;
}

// async 16B global->LDS (per-lane gsrc; LDS dest must be wave-uniform base + lane*16)
DEV void async16(const void* g, void* l) {
  __builtin_amdgcn_global_load_lds(
      (const __attribute__((address_space(1))) unsigned int*)g,
      (__attribute__((address_space(3))) unsigned int*)l, 16, 0, 0);
}

// ---------------- k_prep: Wq/Wk/Wv split-transpose + zero ctx/ksum ----------------
__global__ void k_prep(const float* __restrict__ Wq, const float* __restrict__ Wk,
                       const float* __restrict__ Wv,
                       unsigned short* __restrict__ WTh, unsigned short* __restrict__ WTl,
                       float* __restrict__ ctxz) {
  int gid = blockIdx.x * 256 + threadIdx.x;
  if (gid < 6144) {               // 3 mats x 128 n x 16 k-groups of 8
    int mat = gid >> 11, r = gid & 2047, n = r >> 4, k0 = (r & 15) * 8;
    const float* W = (mat == 0) ? Wq : (mat == 1) ? Wk : Wv;
    union { uint4 q; unsigned short u[8]; } oh, ol;
#pragma unroll
    for (int i = 0; i < 8; ++i) splitf(W[(size_t)(k0 + i) * 128 + n], oh.u[i], ol.u[i]);
    *(uint4*)&WTh[mat * 16384 + n * 128 + k0] = oh.q;
    *(uint4*)&WTl[mat * 16384 + n * 128 + k0] = ol.q;
  } else if (gid < 6144 + 17408) {
    ctxz[gid - 6144] = 0.0f;      // ctx (16384) + ksum (1024)
  }
}

// ---------------- kernel 1: qkv GEMM + rope/elu + q'/ksum/ctx. 512 thr, wave=1 head ----------------
__global__ __launch_bounds__(512, 4) void k_qkv(
    const float* __restrict__ x,
    const unsigned short* __restrict__ WTh, const unsigned short* __restrict__ WTl,
    const float* __restrict__ bq, const float* __restrict__ bk, const float* __restrict__ bv,
    float* __restrict__ ctx, float* __restrict__ ksum,
    unsigned short* __restrict__ qws) {
  // xh/xl in one buffer so the ctx-phase can reuse it as per-wave f32 scratch:
  // 8 waves x (64 rows x 17 f32 x 4B = 4352B) = 34816B = exactly 2*64*XPAD shorts.
  __shared__ __align__(16) unsigned short xbuf[2 * 64 * XPAD];
  __shared__ float rc[64][9], rs[64][9];
  unsigned short* xh = xbuf;
  unsigned short* xl = xbuf + 64 * XPAD;
  const int tid = threadIdx.x;
  const int row0 = blockIdx.x * 64;
  const int b = row0 >> 13;
  const int t0 = row0 & 8191;

  {  // rope table: 512 threads -> 64 rows x 8 j
    int r = tid >> 3, j = tid & 7;
    float invf = 1.0f / powf(10000.0f, (float)j * 0.125f);
    float s, c;
    sincosf((float)(t0 + r) * invf, &s, &c);
    rc[r][j] = c; rs[r][j] = s;
  }
  {  // stage x, split ONCE per element
    int r = tid >> 3, cg = (tid & 7) * 16;
    const float* xp = x + (size_t)(row0 + r) * 128 + cg;
    short8 h0, l0, h1, l1;
    split8(xp, h0, l0);
    split8(xp + 8, h1, l1);
    *(short8*)&xh[r * XPAD + cg] = h0;
    *(short8*)&xh[r * XPAD + cg + 8] = h1;
    *(short8*)&xl[r * XPAD + cg] = l0;
    *(short8*)&xl[r * XPAD + cg + 8] = l1;
  }
  __syncthreads();

  const int l = tid & 63, w = tid >> 6;       // wave w owns head w
  const int lane16 = l & 15, quad = l >> 4;

  floatx4 acc[3][4];               // [mat: q,k,v][mt]  = 48 AGPRs
#pragma unroll
  for (int i = 0; i < 3; ++i)
#pragma unroll
    for (int j = 0; j < 4; ++j) acc[i][j] = (floatx4){0.f, 0.f, 0.f, 0.f};

  // weight base offsets per mat (ks advances by +32 shorts)
  size_t wbase[3];
#pragma unroll
  for (int mat = 0; mat < 3; ++mat)
    wbase[mat] = (size_t)mat * 16384 + (size_t)(w * 16 + lane16) * 128 + quad * 8;

  // double-buffered weight frags: prefetch ks+1 while computing ks
  short8 wh[2][3], wl[2][3];
#pragma unroll
  for (int mat = 0; mat < 3; ++mat) {
    wh[0][mat] = *(const short8*)(WTh + wbase[mat]);
    wl[0][mat] = *(const short8*)(WTl + wbase[mat]);
  }

#pragma unroll
  for (int ks = 0; ks < 4; ++ks) {
    const int cur = ks & 1, nxt = cur ^ 1;
    if (ks < 3) {
#pragma unroll
      for (int mat = 0; mat < 3; ++mat) {
        wh[nxt][mat] = *(const short8*)(WTh + wbase[mat] + (ks + 1) * 32);
        wl[nxt][mat] = *(const short8*)(WTl + wbase[mat] + (ks + 1) * 32);
      }
    }
    short8 afh[4], afl[4];
#pragma unroll
    for (int mt = 0; mt < 4; ++mt) {
      int off = (mt * 16 + lane16) * XPAD + ks * 32 + quad * 8;
      afh[mt] = *(const short8*)&xh[off];
      afl[mt] = *(const short8*)&xl[off];
    }
#pragma unroll
    for (int mat = 0; mat < 3; ++mat) {
#pragma unroll
      for (int mt = 0; mt < 4; ++mt) {
        acc[mat][mt] = MFMA(afh[mt], wh[cur][mat], acc[mat][mt], 0, 0, 0);
        acc[mat][mt] = MFMA(afl[mt], wh[cur][mat], acc[mat][mt], 0, 0, 0);
        acc[mat][mt] = MFMA(afh[mt], wl[cur][mat], acc[mat][mt], 0, 0, 0);
      }
    }
  }

  // bias (lane16 = col within head)
  {
    int col = w * 16 + lane16;
    float bias[3] = {bq[col], bk[col], bv[col]};
#pragma unroll
    for (int mat = 0; mat < 3; ++mat)
#pragma unroll
      for (int mt = 0; mt < 4; ++mt)
#pragma unroll
        for (int r = 0; r < 4; ++r) acc[mat][mt][r] += bias[mat];
  }

  // rope + elu+1 on q (mat 0) and k (mat 1). lane16 = d; t = mt*16 + quad*4 + r.
  {
    const int d = lane16, j = d & 7;
#pragma unroll
    for (int mt = 0; mt < 4; ++mt) {
      float cc[4], ss[4];
#pragma unroll
      for (int r = 0; r < 4; ++r) {
        int tl = mt * 16 + quad * 4 + r;
        cc[r] = rc[tl][j]; ss[r] = rs[tl][j];
      }
#pragma unroll
      for (int mat = 0; mat < 2; ++mat) {
#pragma unroll
        for (int r = 0; r < 4; ++r) {
          float v = acc[mat][mt][r];
          float p = __shfl_xor(v, 8);          // pair (d, d+8)
          float nv = (d < 8) ? (v * cc[r] - p * ss[r]) : (p * ss[r] + v * cc[r]);
          acc[mat][mt][r] = (nv > 0.f) ? (nv + 1.f) : __expf(nv);
        }
      }
    }
  }

  // ksum[h=w][d] from k
  {
    float s = 0.f;
#pragma unroll
    for (int mt = 0; mt < 4; ++mt)
#pragma unroll
      for (int r = 0; r < 4; ++r) s += acc[1][mt][r];
    s += __shfl_xor(s, 16);
    s += __shfl_xor(s, 32);
    if (l < 16) atomicAdd(&ksum[(b * 8 + w) * 16 + lane16], s);
  }

  // q' -> ws bf16 [t][128]
#pragma unroll
  for (int mt = 0; mt < 4; ++mt)
#pragma unroll
    for (int r = 0; r < 4; ++r)
      qws[(size_t)(row0 + mt * 16 + quad * 4 + r) * 128 + w * 16 + lane16] =
          bfh(acc[0][mt][r]);

  __syncthreads();   // all waves done reading xh/xl -> safe to reuse as scratch

  // ctx[h=w] += K^T V via LDS transpose. Frag semantics identical to the verified
  // xpose_frag: F[d=lane16][k-slot j] = M[t = win*32 + quad*8 + j][d].
  {
    float* S = ((float*)xbuf) + w * 1088;    // 64 rows x 17 f32, per-wave slice
    // K tile -> scratch [t][d], pad 17 (reads 2-way conflict-free, writes ~4-way)
#pragma unroll
    for (int mt = 0; mt < 4; ++mt)
#pragma unroll
      for (int r = 0; r < 4; ++r)
        S[(mt * 16 + quad * 4 + r) * 17 + lane16] = acc[1][mt][r];
    short8 kh[2], kl[2];
#pragma unroll
    for (int win = 0; win < 2; ++win) {
      union { short8 s; unsigned short u[8]; } H, L;
#pragma unroll
      for (int j = 0; j < 8; ++j) {
        float v = S[(win * 32 + quad * 8 + j) * 17 + lane16];
        splitf(v, H.u[j], L.u[j]);
      }
      kh[win] = H.s; kl[win] = L.s;
    }
    // V tile -> same scratch (per-wave DS pipe is in-order; compiler orders aliases)
#pragma unroll
    for (int mt = 0; mt < 4; ++mt)
#pragma unroll
      for (int r = 0; r < 4; ++r)
        S[(mt * 16 + quad * 4 + r) * 17 + lane16] = acc[2][mt][r];
    floatx4 c = (floatx4){0.f, 0.f, 0.f, 0.f};
#pragma unroll
    for (int win = 0; win < 2; ++win) {
      union { short8 s; unsigned short u[8]; } H, L;
#pragma unroll
      for (int j = 0; j < 8; ++j) {
        float v = S[(win * 32 + quad * 8 + j) * 17 + lane16];
        splitf(v, H.u[j], L.u[j]);
      }
      c = MFMA(kh[win], H.s, c, 0, 0, 0);
      c = MFMA(kl[win], H.s, c, 0, 0, 0);
      c = MFMA(kh[win], L.s, c, 0, 0, 0);
    }
#pragma unroll
    for (int r = 0; r < 4; ++r)
      atomicAdd(&ctx[((size_t)(b * 8 + w) * 16 + quad * 4 + r) * 16 + lane16], c[r]);
  }
}

// ---------------- k_mprep: M = C_h @ Wo_h (fp32) -> frag-major permuted split-bf16 ----------------
// Consumer frag (nt,ks), lane l reads 16B at group ((nt*4+ks)*64 + l); element j = qc ks*32+(l>>4)*8+j.
__global__ void k_mprep(const float* __restrict__ Wo, const float* __restrict__ ctx,
                        unsigned short* __restrict__ MTh, unsigned short* __restrict__ MTl) {
  int gid = blockIdx.x * 256 + threadIdx.x;   // 64 blocks: 8 b x 128 oc x 16 qc-groups
  int b = gid >> 11, r = gid & 2047, oc = r >> 4, qcg = r & 15;
  int h = qcg >> 1, d0 = (qcg & 1) * 8;
  const float* C = ctx + (size_t)(b * 8 + h) * 256;   // [d][e]
  float m[8] = {0.f, 0.f, 0.f, 0.f, 0.f, 0.f, 0.f, 0.f};
#pragma unroll 4
  for (int e = 0; e < 16; ++e) {
    float wv = Wo[(size_t)(h * 16 + e) * 128 + oc];
#pragma unroll
    for (int i = 0; i < 8; ++i) m[i] += C[(d0 + i) * 16 + e] * wv;
  }
  union { uint4 q; unsigned short u[8]; } oh, ol;
#pragma unroll
  for (int i = 0; i < 8; ++i) splitf(m[i], oh.u[i], ol.u[i]);
  // permuted group index: nt=oc>>4, ks=qcg>>2, l = (qcg&3)*16 + (oc&15)
  int grp = (((oc >> 4) * 4 + (qcg >> 2)) * 64) + (qcg & 3) * 16 + (oc & 15);
  *(uint4*)&MTh[(size_t)b * 16384 + grp * 8] = oh.q;
  *(uint4*)&MTl[(size_t)b * 16384 + grp * 8] = ol.q;
}

// ---------------- kernel 2: out = (z .* q') @ M + bo. M staged in LDS. ----------------
// 512 blocks x 512 thr (8 waves); block = 128 rows, wave w = one 16-row m-tile.
// A-frag prologue runs BEFORE the staging barrier (ksum read from global, L2-broadcast)
// so its qws-load + splitf latency hides under the 64KB global_load_lds drain.
__global__ __launch_bounds__(512) void k_zout(
    const unsigned short* __restrict__ qws,
    const unsigned short* __restrict__ MTh, const unsigned short* __restrict__ MTl,
    const float* __restrict__ bo, const float* __restrict__ ksum,
    float* __restrict__ out) {
  __shared__ __align__(16) unsigned short mh[16384], ml[16384];  // 32KB + 32KB, frag-major
  __shared__ float boS[128];
  const int tid = threadIdx.x;
  const int row0 = blockIdx.x * 128;
  const int b = row0 >> 13;
  const int l = tid & 63, w = tid >> 6;
  const int lane16 = l & 15, quad = l >> 4;

  {  // issue async M staging first: wave w copies chunks (i*8+w)*1KB
    const char* gh = (const char*)(MTh + (size_t)b * 16384);
    const char* gl = (const char*)(MTl + (size_t)b * 16384);
#pragma unroll
    for (int i = 0; i < 4; ++i) {
      int off = (i * 8 + w) * 1024 + l * 16;
      async16(gh + off, (char*)mh + off);
      async16(gl + off, (char*)ml + off);
    }
  }
  if (tid >= 128 && tid < 256) boS[tid - 128] = bo[tid - 128];

  // A-frags: q' from ws (frag-layout), z in-reg, scale+split — overlapped with staging
  short8 ah[4], al[4];
  {
    int trow = row0 + w * 16 + lane16;      // lane16 = t within the wave's 16-row strip
    const float* kg = ksum + b * 128;
#pragma unroll
    for (int ks = 0; ks < 4; ++ks) {
      union { short8 s8; unsigned short u[8]; } qq;
      qq.s8 = *(const short8*)&qws[(size_t)trow * 128 + ks * 32 + quad * 8];
      int kb = ks * 32 + quad * 8;
      float4 kf0 = *(const float4*)(kg + kb);
      float4 kf1 = *(const float4*)(kg + kb + 4);
      float kf[8] = {kf0.x, kf0.y, kf0.z, kf0.w, kf1.x, kf1.y, kf1.z, kf1.w};
      float s = 0.f;
#pragma unroll
      for (int j = 0; j < 8; ++j) s += bfdec(qq.u[j]) * kf[j];
      s += __shfl_xor(s, 16);        // combine the two 8-halves of the head
      float z = 1.0f / (s + 1e-6f);
      union { short8 s8; unsigned short u[8]; } H, L;
#pragma unroll
      for (int j = 0; j < 8; ++j) splitf(bfdec(qq.u[j]) * z, H.u[j], L.u[j]);
      ah[ks] = H.s8;
      al[ks] = L.s8;
    }
  }
  __syncthreads();                 // drains async staging (prologue hidden under it)

  floatx4 oacc[8];
#pragma unroll
  for (int i = 0; i < 8; ++i) oacc[i] = (floatx4){0.f, 0.f, 0.f, 0.f};

#pragma unroll
  for (int nt = 0; nt < 8; ++nt) {
#pragma unroll
    for (int ks = 0; ks < 4; ++ks) {
      int moff = ((nt * 4 + ks) * 64 + l) * 8;        // frag-major: lane-contiguous 16B
      short8 wbh = *(const short8*)&mh[moff];
      short8 wbl = *(const short8*)&ml[moff];
      oacc[nt] = MFMA(ah[ks], wbh, oacc[nt], 0, 0, 0);
      oacc[nt] = MFMA(al[ks], wbh, oacc[nt], 0, 0, 0);
      oacc[nt] = MFMA(ah[ks], wbl, oacc[nt], 0, 0, 0);
    }
  }

#pragma unroll
  for (int nt = 0; nt < 8; ++nt) {
    int oc = nt * 16 + lane16;
    float bb = boS[oc];
#pragma unroll
    for (int r = 0; r < 4; ++r) {
      int t = row0 + w * 16 + quad * 4 + r;
      out[(size_t)t * 128 + oc] = oacc[nt][r] + bb;
    }
  }
}

extern "C" void kernel_launch(void* const* d_in, const int* in_sizes, int n_in,
                              void* d_out, int out_size, void* d_ws, size_t ws_size,
                              hipStream_t stream) {
  const float* x  = (const float*)d_in[0];
  const float* Wq = (const float*)d_in[1];
  const float* bq = (const float*)d_in[2];
  const float* Wk = (const float*)d_in[3];
  const float* bk = (const float*)d_in[4];
  const float* Wv = (const float*)d_in[5];
  const float* bv = (const float*)d_in[6];
  const float* Wo = (const float*)d_in[7];
  const float* bo = (const float*)d_in[8];
  float* out = (float*)d_out;

  // ws: qws 16.78MB | WTh 96KB | WTl 96KB | ctx 64KB | ksum 4KB | MTh 256KB | MTl 256KB
  unsigned short* qws = (unsigned short*)d_ws;         // 65536*128 shorts
  unsigned short* WTh = qws + 8388608;                 // 3 x 16384
  unsigned short* WTl = WTh + 49152;
  float* ctx  = (float*)(WTl + 49152);                 // 16384 f
  float* ksum = ctx + 16384;                           // 1024 f
  unsigned short* MTh = (unsigned short*)(ksum + 1024);  // 8 x 16384
  unsigned short* MTl = MTh + 131072;

  k_prep<<<92, 256, 0, stream>>>(Wq, Wk, Wv, WTh, WTl, ctx);
  k_qkv<<<1024, 512, 0, stream>>>(x, WTh, WTl, bq, bk, bv, ctx, ksum, qws);
  k_mprep<<<64, 256, 0, stream>>>(Wo, ctx, MTh, MTl);
  k_zout<<<512, 512, 0, stream>>>(qws, MTh, MTl, bo, ksum, out);
}

// Round 8
// 159.045 us; speedup vs baseline: 1.0590x; 1.0480x over previous
//
#include <hip/hip_runtime.h>
#include <hip/hip_bf16.h>

// LightningAttention MI355X — round 16.
// R15 post-mortem: LDS-transpose variant spilled to scratch (+80MB/dispatch HBM traffic,
//   FETCH 17->44MB WRITE 25->78MB) -> revert k_qkv to R13-exact (58.5us anchor).
//   SQ_LDS_BANK_CONFLICT = 2,916,352 bit-identical with bpermutes REMOVED -> conflicts
//   are invariant to both tile stride and crossbar; stop chasing that counter.
// New in R16: RoPE trig hoisted to k_prep (full [T][8] cos/sin table, 512KB ws, built
//   once = 65K sincosf instead of 524K per k_qkv dispatch, out of the pre-barrier
//   prologue). k_qkv rope table = coalesced 8B/thread load. Bit-identical math.
// k_zout keeps R15's hoisted prologue (rest-of-budget 98.7 vs 102.1 -> ~3us win).
// B=8 T=8192 DM=128 H=8 Dh=16. Split-bf16 (hi+lo) on all MFMA surfaces except q' (bf16).

typedef __attribute__((ext_vector_type(8))) short short8;   // 8 bf16 (MFMA A/B frag)
typedef __attribute__((ext_vector_type(4))) float floatx4;  // MFMA C/D frag

#define DEV __device__ __forceinline__
#define MFMA __builtin_amdgcn_mfma_f32_16x16x32_bf16

#define XPAD 136   // x-tile row stride in shorts. 136 -> LDS 39424B. Do not grow.

DEV unsigned short bfh(float f) {
  unsigned int x = __float_as_uint(f);
  x += 0x7fffu + ((x >> 16) & 1u);     // RNE
  return (unsigned short)(x >> 16);
}
DEV float bfdec(unsigned short u) { return __uint_as_float(((unsigned int)u) << 16); }
DEV void splitf(float f, unsigned short& h, unsigned short& l) {
  h = bfh(f);
  l = bfh(f - bfdec(h));
}
DEV void split8(const float* p, short8& h8, short8& l8) {
  float4 a = *(const float4*)p;
  float4 b = *(const float4*)(p + 4);
  float v[8] = {a.x, a.y, a.z, a.w, b.x, b.y, b.z, b.w};
  union { short8 s; unsigned short u[8]; } H, L;
#pragma unroll
  for (int i = 0; i < 8; ++i) splitf(v[i], H.u[i], L.u[i]);
  h8 = H.s; l8 = L.s;
}

// Register transpose (verified R5-R7): C-layout tile val(n=lane16, m=mt*16+quad*4+r),
// rows m0/m1 -> split frag F[lane16][k=quad*8+j] over the 32-wide m-window.
DEV void xpose_frag(floatx4 m0, floatx4 m1, int lane16, int quad,
                    short8& hi, short8& lo) {
  union { short8 s; unsigned short u[8]; } H, L;
#pragma unroll
  for (int j = 0; j < 8; ++j) {
    int srcLane = lane16 + (((quad & 1) * 2 + (j >> 2)) << 4);
    float vA = __shfl(m0[j & 3], srcLane, 64);
    float vB = __shfl(m1[j & 3], srcLane, 64);
    float v = (quad < 2) ? vA : vB;
    splitf(v, H.u[j], L.u[j]);
  }
  hi = H.s; lo = L.s;
}

// async 16B global->LDS (per-lane gsrc; LDS dest must be wave-uniform base + lane*16)
DEV void async16(const void* g, void* l) {
  __builtin_amdgcn_global_load_lds(
      (const __attribute__((address_space(1))) unsigned int*)g,
      (__attribute__((address_space(3))) unsigned int*)l, 16, 0, 0);
}

// ---------------- k_prep: Wq/Wk/Wv split-transpose + zero ctx/ksum + rope table ----------------
__global__ void k_prep(const float* __restrict__ Wq, const float* __restrict__ Wk,
                       const float* __restrict__ Wv,
                       unsigned short* __restrict__ WTh, unsigned short* __restrict__ WTl,
                       float* __restrict__ ctxz,
                       float* __restrict__ RC, float* __restrict__ RS) {
  int gid = blockIdx.x * 256 + threadIdx.x;
  if (gid < 6144) {               // 3 mats x 128 n x 16 k-groups of 8
    int mat = gid >> 11, r = gid & 2047, n = r >> 4, k0 = (r & 15) * 8;
    const float* W = (mat == 0) ? Wq : (mat == 1) ? Wk : Wv;
    union { uint4 q; unsigned short u[8]; } oh, ol;
#pragma unroll
    for (int i = 0; i < 8; ++i) splitf(W[(size_t)(k0 + i) * 128 + n], oh.u[i], ol.u[i]);
    *(uint4*)&WTh[mat * 16384 + n * 128 + k0] = oh.q;
    *(uint4*)&WTl[mat * 16384 + n * 128 + k0] = ol.q;
  } else if (gid < 6144 + 17408) {
    ctxz[gid - 6144] = 0.0f;      // ctx (16384) + ksum (1024)
  } else if (gid < 23552 + 65536) {
    int idx = gid - 23552;        // t*8 + j, T=8192
    int t = idx >> 3, j = idx & 7;
    float invf = 1.0f / powf(10000.0f, (float)j * 0.125f);
    float s, c;
    sincosf((float)t * invf, &s, &c);
    RC[idx] = c; RS[idx] = s;     // bit-identical to the old per-block computation
  }
}

// ---------------- kernel 1: qkv GEMM + rope/elu + q'/ksum/ctx. 512 thr, wave=1 head ----------------
__global__ __launch_bounds__(512) void k_qkv(
    const float* __restrict__ x,
    const unsigned short* __restrict__ WTh, const unsigned short* __restrict__ WTl,
    const float* __restrict__ bq, const float* __restrict__ bk, const float* __restrict__ bv,
    const float* __restrict__ RC, const float* __restrict__ RS,
    float* __restrict__ ctx, float* __restrict__ ksum,
    unsigned short* __restrict__ qws) {
  __shared__ unsigned short xh[64 * XPAD], xl[64 * XPAD];   // pre-split x tile [row][k]
  __shared__ float rc[64][9], rs[64][9];
  const int tid = threadIdx.x;
  const int row0 = blockIdx.x * 64;
  const int b = row0 >> 13;
  const int t0 = row0 & 8191;

  {  // rope table: coalesced load from precomputed global table (no trig)
    int r = tid >> 3, j = tid & 7;
    int idx = (t0 + r) * 8 + j;
    rc[r][j] = RC[idx];
    rs[r][j] = RS[idx];
  }
  {  // stage x, split ONCE per element
    int r = tid >> 3, cg = (tid & 7) * 16;
    const float* xp = x + (size_t)(row0 + r) * 128 + cg;
    short8 h0, l0, h1, l1;
    split8(xp, h0, l0);
    split8(xp + 8, h1, l1);
    *(short8*)&xh[r * XPAD + cg] = h0;
    *(short8*)&xh[r * XPAD + cg + 8] = h1;
    *(short8*)&xl[r * XPAD + cg] = l0;
    *(short8*)&xl[r * XPAD + cg + 8] = l1;
  }
  __syncthreads();                 // only barrier

  const int l = tid & 63, w = tid >> 6;       // wave w owns head w
  const int lane16 = l & 15, quad = l >> 4;

  floatx4 acc[3][4];               // [mat: q,k,v][mt]  = 48 AGPRs
#pragma unroll
  for (int i = 0; i < 3; ++i)
#pragma unroll
    for (int j = 0; j < 4; ++j) acc[i][j] = (floatx4){0.f, 0.f, 0.f, 0.f};

  // weight base offsets per mat (ks advances by +32 shorts)
  size_t wbase[3];
#pragma unroll
  for (int mat = 0; mat < 3; ++mat)
    wbase[mat] = (size_t)mat * 16384 + (size_t)(w * 16 + lane16) * 128 + quad * 8;

  // double-buffered weight frags: prefetch ks+1 while computing ks
  short8 wh[2][3], wl[2][3];
#pragma unroll
  for (int mat = 0; mat < 3; ++mat) {
    wh[0][mat] = *(const short8*)(WTh + wbase[mat]);
    wl[0][mat] = *(const short8*)(WTl + wbase[mat]);
  }

#pragma unroll
  for (int ks = 0; ks < 4; ++ks) {
    const int cur = ks & 1, nxt = cur ^ 1;
    if (ks < 3) {
#pragma unroll
      for (int mat = 0; mat < 3; ++mat) {
        wh[nxt][mat] = *(const short8*)(WTh + wbase[mat] + (ks + 1) * 32);
        wl[nxt][mat] = *(const short8*)(WTl + wbase[mat] + (ks + 1) * 32);
      }
    }
    short8 afh[4], afl[4];
#pragma unroll
    for (int mt = 0; mt < 4; ++mt) {
      int off = (mt * 16 + lane16) * XPAD + ks * 32 + quad * 8;
      afh[mt] = *(const short8*)&xh[off];
      afl[mt] = *(const short8*)&xl[off];
    }
#pragma unroll
    for (int mat = 0; mat < 3; ++mat) {
#pragma unroll
      for (int mt = 0; mt < 4; ++mt) {
        acc[mat][mt] = MFMA(afh[mt], wh[cur][mat], acc[mat][mt], 0, 0, 0);
        acc[mat][mt] = MFMA(afl[mt], wh[cur][mat], acc[mat][mt], 0, 0, 0);
        acc[mat][mt] = MFMA(afh[mt], wl[cur][mat], acc[mat][mt], 0, 0, 0);
      }
    }
  }

  // bias (lane16 = col within head)
  {
    int col = w * 16 + lane16;
    float bias[3] = {bq[col], bk[col], bv[col]};
#pragma unroll
    for (int mat = 0; mat < 3; ++mat)
#pragma unroll
      for (int mt = 0; mt < 4; ++mt)
#pragma unroll
        for (int r = 0; r < 4; ++r) acc[mat][mt][r] += bias[mat];
  }

  // rope + elu+1 on q (mat 0) and k (mat 1). lane16 = d; t = mt*16 + quad*4 + r.
  {
    const int d = lane16, j = d & 7;
#pragma unroll
    for (int mt = 0; mt < 4; ++mt) {
      float cc[4], ss[4];
#pragma unroll
      for (int r = 0; r < 4; ++r) {
        int tl = mt * 16 + quad * 4 + r;
        cc[r] = rc[tl][j]; ss[r] = rs[tl][j];
      }
#pragma unroll
      for (int mat = 0; mat < 2; ++mat) {
#pragma unroll
        for (int r = 0; r < 4; ++r) {
          float v = acc[mat][mt][r];
          float p = __shfl_xor(v, 8);          // pair (d, d+8)
          float nv = (d < 8) ? (v * cc[r] - p * ss[r]) : (p * ss[r] + v * cc[r]);
          acc[mat][mt][r] = (nv > 0.f) ? (nv + 1.f) : __expf(nv);
        }
      }
    }
  }

  // ksum[h=w][d] from k
  {
    float s = 0.f;
#pragma unroll
    for (int mt = 0; mt < 4; ++mt)
#pragma unroll
      for (int r = 0; r < 4; ++r) s += acc[1][mt][r];
    s += __shfl_xor(s, 16);
    s += __shfl_xor(s, 32);
    if (l < 16) atomicAdd(&ksum[(b * 8 + w) * 16 + lane16], s);
  }

  // q' -> ws bf16 [t][128]
#pragma unroll
  for (int mt = 0; mt < 4; ++mt)
#pragma unroll
    for (int r = 0; r < 4; ++r)
      qws[(size_t)(row0 + mt * 16 + quad * 4 + r) * 128 + w * 16 + lane16] =
          bfh(acc[0][mt][r]);

  // ctx[h=w] += K^T V via register transposes (2 t-windows of 32)
  {
    floatx4 c = (floatx4){0.f, 0.f, 0.f, 0.f};
#pragma unroll
    for (int ks2 = 0; ks2 < 2; ++ks2) {
      short8 kh, kl, vh, vl;
      xpose_frag(acc[1][ks2 * 2], acc[1][ks2 * 2 + 1], lane16, quad, kh, kl);
      xpose_frag(acc[2][ks2 * 2], acc[2][ks2 * 2 + 1], lane16, quad, vh, vl);
      c = MFMA(kh, vh, c, 0, 0, 0);
      c = MFMA(kl, vh, c, 0, 0, 0);
      c = MFMA(kh, vl, c, 0, 0, 0);
    }
#pragma unroll
    for (int r = 0; r < 4; ++r)
      atomicAdd(&ctx[((size_t)(b * 8 + w) * 16 + quad * 4 + r) * 16 + lane16], c[r]);
  }
}

// ---------------- k_mprep: M = C_h @ Wo_h (fp32) -> frag-major permuted split-bf16 ----------------
// Consumer frag (nt,ks), lane l reads 16B at group ((nt*4+ks)*64 + l); element j = qc ks*32+(l>>4)*8+j.
__global__ void k_mprep(const float* __restrict__ Wo, const float* __restrict__ ctx,
                        unsigned short* __restrict__ MTh, unsigned short* __restrict__ MTl) {
  int gid = blockIdx.x * 256 + threadIdx.x;   // 64 blocks: 8 b x 128 oc x 16 qc-groups
  int b = gid >> 11, r = gid & 2047, oc = r >> 4, qcg = r & 15;
  int h = qcg >> 1, d0 = (qcg & 1) * 8;
  const float* C = ctx + (size_t)(b * 8 + h) * 256;   // [d][e]
  float m[8] = {0.f, 0.f, 0.f, 0.f, 0.f, 0.f, 0.f, 0.f};
#pragma unroll 4
  for (int e = 0; e < 16; ++e) {
    float wv = Wo[(size_t)(h * 16 + e) * 128 + oc];
#pragma unroll
    for (int i = 0; i < 8; ++i) m[i] += C[(d0 + i) * 16 + e] * wv;
  }
  union { uint4 q; unsigned short u[8]; } oh, ol;
#pragma unroll
  for (int i = 0; i < 8; ++i) splitf(m[i], oh.u[i], ol.u[i]);
  // permuted group index: nt=oc>>4, ks=qcg>>2, l = (qcg&3)*16 + (oc&15)
  int grp = (((oc >> 4) * 4 + (qcg >> 2)) * 64) + (qcg & 3) * 16 + (oc & 15);
  *(uint4*)&MTh[(size_t)b * 16384 + grp * 8] = oh.q;
  *(uint4*)&MTl[(size_t)b * 16384 + grp * 8] = ol.q;
}

// ---------------- kernel 2: out = (z .* q') @ M + bo. M staged in LDS. ----------------
// 512 blocks x 512 thr (8 waves); block = 128 rows, wave w = one 16-row m-tile.
// A-frag prologue runs BEFORE the staging barrier (ksum read from global, L2-broadcast)
// so its qws-load + splitf latency hides under the 64KB global_load_lds drain.
__global__ __launch_bounds__(512) void k_zout(
    const unsigned short* __restrict__ qws,
    const unsigned short* __restrict__ MTh, const unsigned short* __restrict__ MTl,
    const float* __restrict__ bo, const float* __restrict__ ksum,
    float* __restrict__ out) {
  __shared__ __align__(16) unsigned short mh[16384], ml[16384];  // 32KB + 32KB, frag-major
  __shared__ float boS[128];
  const int tid = threadIdx.x;
  const int row0 = blockIdx.x * 128;
  const int b = row0 >> 13;
  const int l = tid & 63, w = tid >> 6;
  const int lane16 = l & 15, quad = l >> 4;

  {  // issue async M staging first: wave w copies chunks (i*8+w)*1KB
    const char* gh = (const char*)(MTh + (size_t)b * 16384);
    const char* gl = (const char*)(MTl + (size_t)b * 16384);
#pragma unroll
    for (int i = 0; i < 4; ++i) {
      int off = (i * 8 + w) * 1024 + l * 16;
      async16(gh + off, (char*)mh + off);
      async16(gl + off, (char*)ml + off);
    }
  }
  if (tid >= 128 && tid < 256) boS[tid - 128] = bo[tid - 128];

  // A-frags: q' from ws (frag-layout), z in-reg, scale+split — overlapped with staging
  short8 ah[4], al[4];
  {
    int trow = row0 + w * 16 + lane16;      // lane16 = t within the wave's 16-row strip
    const float* kg = ksum + b * 128;
#pragma unroll
    for (int ks = 0; ks < 4; ++ks) {
      union { short8 s8; unsigned short u[8]; } qq;
      qq.s8 = *(const short8*)&qws[(size_t)trow * 128 + ks * 32 + quad * 8];
      int kb = ks * 32 + quad * 8;
      float4 kf0 = *(const float4*)(kg + kb);
      float4 kf1 = *(const float4*)(kg + kb + 4);
      float kf[8] = {kf0.x, kf0.y, kf0.z, kf0.w, kf1.x, kf1.y, kf1.z, kf1.w};
      float s = 0.f;
#pragma unroll
      for (int j = 0; j < 8; ++j) s += bfdec(qq.u[j]) * kf[j];
      s += __shfl_xor(s, 16);        // combine the two 8-halves of the head
      float z = 1.0f / (s + 1e-6f);
      union { short8 s8; unsigned short u[8]; } H, L;
#pragma unroll
      for (int j = 0; j < 8; ++j) splitf(bfdec(qq.u[j]) * z, H.u[j], L.u[j]);
      ah[ks] = H.s8;
      al[ks] = L.s8;
    }
  }
  __syncthreads();                 // drains async staging (prologue hidden under it)

  floatx4 oacc[8];
#pragma unroll
  for (int i = 0; i < 8; ++i) oacc[i] = (floatx4){0.f, 0.f, 0.f, 0.f};

#pragma unroll
  for (int nt = 0; nt < 8; ++nt) {
#pragma unroll
    for (int ks = 0; ks < 4; ++ks) {
      int moff = ((nt * 4 + ks) * 64 + l) * 8;        // frag-major: lane-contiguous 16B
      short8 wbh = *(const short8*)&mh[moff];
      short8 wbl = *(const short8*)&ml[moff];
      oacc[nt] = MFMA(ah[ks], wbh, oacc[nt], 0, 0, 0);
      oacc[nt] = MFMA(al[ks], wbh, oacc[nt], 0, 0, 0);
      oacc[nt] = MFMA(ah[ks], wbl, oacc[nt], 0, 0, 0);
    }
  }

#pragma unroll
  for (int nt = 0; nt < 8; ++nt) {
    int oc = nt * 16 + lane16;
    float bb = boS[oc];
#pragma unroll
    for (int r = 0; r < 4; ++r) {
      int t = row0 + w * 16 + quad * 4 + r;
      out[(size_t)t * 128 + oc] = oacc[nt][r] + bb;
    }
  }
}

extern "C" void kernel_launch(void* const* d_in, const int* in_sizes, int n_in,
                              void* d_out, int out_size, void* d_ws, size_t ws_size,
                              hipStream_t stream) {
  const float* x  = (const float*)d_in[0];
  const float* Wq = (const float*)d_in[1];
  const float* bq = (const float*)d_in[2];
  const float* Wk = (const float*)d_in[3];
  const float* bk = (const float*)d_in[4];
  const float* Wv = (const float*)d_in[5];
  const float* bv = (const float*)d_in[6];
  const float* Wo = (const float*)d_in[7];
  const float* bo = (const float*)d_in[8];
  float* out = (float*)d_out;

  // ws: qws 16.78MB | WTh 96KB | WTl 96KB | ctx 64KB | ksum 4KB | MTh 256KB | MTl 256KB
  //     | RC 256KB | RS 256KB (rope tables)
  unsigned short* qws = (unsigned short*)d_ws;         // 65536*128 shorts
  unsigned short* WTh = qws + 8388608;                 // 3 x 16384
  unsigned short* WTl = WTh + 49152;
  float* ctx  = (float*)(WTl + 49152);                 // 16384 f
  float* ksum = ctx + 16384;                           // 1024 f
  unsigned short* MTh = (unsigned short*)(ksum + 1024);  // 8 x 16384
  unsigned short* MTl = MTh + 131072;
  float* RC = (float*)(MTl + 131072);                  // 65536 f
  float* RS = RC + 65536;                              // 65536 f

  k_prep<<<348, 256, 0, stream>>>(Wq, Wk, Wv, WTh, WTl, ctx, RC, RS);
  k_qkv<<<1024, 512, 0, stream>>>(x, WTh, WTl, bq, bk, bv, RC, RS, ctx, ksum, qws);
  k_mprep<<<64, 256, 0, stream>>>(Wo, ctx, MTh, MTl);
  k_zout<<<512, 512, 0, stream>>>(qws, MTh, MTl, bo, ksum, out);
}

// Round 10
// 158.805 us; speedup vs baseline: 1.0606x; 1.0015x over previous
//
#include <hip/hip_runtime.h>
#include <hip/hip_bf16.h>

// LightningAttention MI355X — round 18.
// R17 post-mortem: cooperative mega-kernel RACED (absmax 5.3e-2; cross-phase visibility
//   on gfx950's non-coherent per-XCD L2s + cooperative launch is graph-capture-hostile).
//   Fusion must happen along dependency edges with real kernel boundaries.
// R18 = R16 (best: 159.0us; k_qkv anchor untouched) with k_mprep FOLDED INTO k_zout:
//   each k_zout block computes its own batch's M = ctx_b @ Wo directly into LDS
//   (ctx_b = 8KB async16-staged; Wo L2-broadcast, coalesced; e-loop order identical to
//   old k_mprep -> bit-identical absmax). Removes: 1 dispatch + its gap, the MTh/MTl
//   512KB global round-trip, and the 64KB async16 M staging.
// 3 dispatches: k_prep | k_qkv | k_zout.
// B=8 T=8192 DM=128 H=8 Dh=16. Split-bf16 (hi+lo) on all MFMA surfaces except q' (bf16).

typedef __attribute__((ext_vector_type(8))) short short8;   // 8 bf16 (MFMA A/B frag)
typedef __attribute__((ext_vector_type(4))) float floatx4;  // MFMA C/D frag

#define DEV __device__ __forceinline__
#define MFMA __builtin_amdgcn_mfma_f32_16x16x32_bf16

#define XPAD 136   // x-tile row stride in shorts. 136 -> LDS 39424B. Do not grow.

DEV unsigned short bfh(float f) {
  unsigned int x = __float_as_uint(f);
  x += 0x7fffu + ((x >> 16) & 1u);     // RNE
  return (unsigned short)(x >> 16);
}
DEV float bfdec(unsigned short u) { return __uint_as_float(((unsigned int)u) << 16); }
DEV void splitf(float f, unsigned short& h, unsigned short& l) {
  h = bfh(f);
  l = bfh(f - bfdec(h));
}
DEV void split8(const float* p, short8& h8, short8& l8) {
  float4 a = *(const float4*)p;
  float4 b = *(const float4*)(p + 4);
  float v[8] = {a.x, a.y, a.z, a.w, b.x, b.y, b.z, b.w};
  union { short8 s; unsigned short u[8]; } H, L;
#pragma unroll
  for (int i = 0; i < 8; ++i) splitf(v[i], H.u[i], L.u[i]);
  h8 = H.s; l8 = L.s;
}

// Register transpose (verified R5-R7): C-layout tile val(n=lane16, m=mt*16+quad*4+r),
// rows m0/m1 -> split frag F[lane16][k=quad*8+j] over the 32-wide m-window.
DEV void xpose_frag(floatx4 m0, floatx4 m1, int lane16, int quad,
                    short8& hi, short8& lo) {
  union { short8 s; unsigned short u[8]; } H, L;
#pragma unroll
  for (int j = 0; j < 8; ++j) {
    int srcLane = lane16 + (((quad & 1) * 2 + (j >> 2)) << 4);
    float vA = __shfl(m0[j & 3], srcLane, 64);
    float vB = __shfl(m1[j & 3], srcLane, 64);
    float v = (quad < 2) ? vA : vB;
    splitf(v, H.u[j], L.u[j]);
  }
  hi = H.s; lo = L.s;
}

// async 16B global->LDS (per-lane gsrc; LDS dest must be wave-uniform base + lane*16)
DEV void async16(const void* g, void* l) {
  __builtin_amdgcn_global_load_lds(
      (const __attribute__((address_space(1))) unsigned int*)g,
      (__attribute__((address_space(3))) unsigned int*)l, 16, 0, 0);
}

// ---------------- k_prep: Wq/Wk/Wv split-transpose + zero ctx/ksum + rope table ----------------
__global__ void k_prep(const float* __restrict__ Wq, const float* __restrict__ Wk,
                       const float* __restrict__ Wv,
                       unsigned short* __restrict__ WTh, unsigned short* __restrict__ WTl,
                       float* __restrict__ ctxz,
                       float* __restrict__ RC, float* __restrict__ RS) {
  int gid = blockIdx.x * 256 + threadIdx.x;
  if (gid < 6144) {               // 3 mats x 128 n x 16 k-groups of 8
    int mat = gid >> 11, r = gid & 2047, n = r >> 4, k0 = (r & 15) * 8;
    const float* W = (mat == 0) ? Wq : (mat == 1) ? Wk : Wv;
    union { uint4 q; unsigned short u[8]; } oh, ol;
#pragma unroll
    for (int i = 0; i < 8; ++i) splitf(W[(size_t)(k0 + i) * 128 + n], oh.u[i], ol.u[i]);
    *(uint4*)&WTh[mat * 16384 + n * 128 + k0] = oh.q;
    *(uint4*)&WTl[mat * 16384 + n * 128 + k0] = ol.q;
  } else if (gid < 6144 + 17408) {
    ctxz[gid - 6144] = 0.0f;      // ctx (16384) + ksum (1024)
  } else if (gid < 23552 + 65536) {
    int idx = gid - 23552;        // t*8 + j, T=8192
    int t = idx >> 3, j = idx & 7;
    float invf = 1.0f / powf(10000.0f, (float)j * 0.125f);
    float s, c;
    sincosf((float)t * invf, &s, &c);
    RC[idx] = c; RS[idx] = s;     // bit-identical to the old per-block computation
  }
}

// ---------------- kernel 1: qkv GEMM + rope/elu + q'/ksum/ctx. 512 thr, wave=1 head ----------------
__global__ __launch_bounds__(512) void k_qkv(
    const float* __restrict__ x,
    const unsigned short* __restrict__ WTh, const unsigned short* __restrict__ WTl,
    const float* __restrict__ bq, const float* __restrict__ bk, const float* __restrict__ bv,
    const float* __restrict__ RC, const float* __restrict__ RS,
    float* __restrict__ ctx, float* __restrict__ ksum,
    unsigned short* __restrict__ qws) {
  __shared__ unsigned short xh[64 * XPAD], xl[64 * XPAD];   // pre-split x tile [row][k]
  __shared__ float rc[64][9], rs[64][9];
  const int tid = threadIdx.x;
  const int row0 = blockIdx.x * 64;
  const int b = row0 >> 13;
  const int t0 = row0 & 8191;

  {  // rope table: coalesced load from precomputed global table (no trig)
    int r = tid >> 3, j = tid & 7;
    int idx = (t0 + r) * 8 + j;
    rc[r][j] = RC[idx];
    rs[r][j] = RS[idx];
  }
  {  // stage x, split ONCE per element
    int r = tid >> 3, cg = (tid & 7) * 16;
    const float* xp = x + (size_t)(row0 + r) * 128 + cg;
    short8 h0, l0, h1, l1;
    split8(xp, h0, l0);
    split8(xp + 8, h1, l1);
    *(short8*)&xh[r * XPAD + cg] = h0;
    *(short8*)&xh[r * XPAD + cg + 8] = h1;
    *(short8*)&xl[r * XPAD + cg] = l0;
    *(short8*)&xl[r * XPAD + cg + 8] = l1;
  }
  __syncthreads();                 // only barrier

  const int l = tid & 63, w = tid >> 6;       // wave w owns head w
  const int lane16 = l & 15, quad = l >> 4;

  floatx4 acc[3][4];               // [mat: q,k,v][mt]  = 48 AGPRs
#pragma unroll
  for (int i = 0; i < 3; ++i)
#pragma unroll
    for (int j = 0; j < 4; ++j) acc[i][j] = (floatx4){0.f, 0.f, 0.f, 0.f};

  // weight base offsets per mat (ks advances by +32 shorts)
  size_t wbase[3];
#pragma unroll
  for (int mat = 0; mat < 3; ++mat)
    wbase[mat] = (size_t)mat * 16384 + (size_t)(w * 16 + lane16) * 128 + quad * 8;

  // double-buffered weight frags: prefetch ks+1 while computing ks
  short8 wh[2][3], wl[2][3];
#pragma unroll
  for (int mat = 0; mat < 3; ++mat) {
    wh[0][mat] = *(const short8*)(WTh + wbase[mat]);
    wl[0][mat] = *(const short8*)(WTl + wbase[mat]);
  }

#pragma unroll
  for (int ks = 0; ks < 4; ++ks) {
    const int cur = ks & 1, nxt = cur ^ 1;
    if (ks < 3) {
#pragma unroll
      for (int mat = 0; mat < 3; ++mat) {
        wh[nxt][mat] = *(const short8*)(WTh + wbase[mat] + (ks + 1) * 32);
        wl[nxt][mat] = *(const short8*)(WTl + wbase[mat] + (ks + 1) * 32);
      }
    }
    short8 afh[4], afl[4];
#pragma unroll
    for (int mt = 0; mt < 4; ++mt) {
      int off = (mt * 16 + lane16) * XPAD + ks * 32 + quad * 8;
      afh[mt] = *(const short8*)&xh[off];
      afl[mt] = *(const short8*)&xl[off];
    }
#pragma unroll
    for (int mat = 0; mat < 3; ++mat) {
#pragma unroll
      for (int mt = 0; mt < 4; ++mt) {
        acc[mat][mt] = MFMA(afh[mt], wh[cur][mat], acc[mat][mt], 0, 0, 0);
        acc[mat][mt] = MFMA(afl[mt], wh[cur][mat], acc[mat][mt], 0, 0, 0);
        acc[mat][mt] = MFMA(afh[mt], wl[cur][mat], acc[mat][mt], 0, 0, 0);
      }
    }
  }

  // bias (lane16 = col within head)
  {
    int col = w * 16 + lane16;
    float bias[3] = {bq[col], bk[col], bv[col]};
#pragma unroll
    for (int mat = 0; mat < 3; ++mat)
#pragma unroll
      for (int mt = 0; mt < 4; ++mt)
#pragma unroll
        for (int r = 0; r < 4; ++r) acc[mat][mt][r] += bias[mat];
  }

  // rope + elu+1 on q (mat 0) and k (mat 1). lane16 = d; t = mt*16 + quad*4 + r.
  {
    const int d = lane16, j = d & 7;
#pragma unroll
    for (int mt = 0; mt < 4; ++mt) {
      float cc[4], ss[4];
#pragma unroll
      for (int r = 0; r < 4; ++r) {
        int tl = mt * 16 + quad * 4 + r;
        cc[r] = rc[tl][j]; ss[r] = rs[tl][j];
      }
#pragma unroll
      for (int mat = 0; mat < 2; ++mat) {
#pragma unroll
        for (int r = 0; r < 4; ++r) {
          float v = acc[mat][mt][r];
          float p = __shfl_xor(v, 8);          // pair (d, d+8)
          float nv = (d < 8) ? (v * cc[r] - p * ss[r]) : (p * ss[r] + v * cc[r]);
          acc[mat][mt][r] = (nv > 0.f) ? (nv + 1.f) : __expf(nv);
        }
      }
    }
  }

  // ksum[h=w][d] from k
  {
    float s = 0.f;
#pragma unroll
    for (int mt = 0; mt < 4; ++mt)
#pragma unroll
      for (int r = 0; r < 4; ++r) s += acc[1][mt][r];
    s += __shfl_xor(s, 16);
    s += __shfl_xor(s, 32);
    if (l < 16) atomicAdd(&ksum[(b * 8 + w) * 16 + lane16], s);
  }

  // q' -> ws bf16 [t][128]
#pragma unroll
  for (int mt = 0; mt < 4; ++mt)
#pragma unroll
    for (int r = 0; r < 4; ++r)
      qws[(size_t)(row0 + mt * 16 + quad * 4 + r) * 128 + w * 16 + lane16] =
          bfh(acc[0][mt][r]);

  // ctx[h=w] += K^T V via register transposes (2 t-windows of 32)
  {
    floatx4 c = (floatx4){0.f, 0.f, 0.f, 0.f};
#pragma unroll
    for (int ks2 = 0; ks2 < 2; ++ks2) {
      short8 kh, kl, vh, vl;
      xpose_frag(acc[1][ks2 * 2], acc[1][ks2 * 2 + 1], lane16, quad, kh, kl);
      xpose_frag(acc[2][ks2 * 2], acc[2][ks2 * 2 + 1], lane16, quad, vh, vl);
      c = MFMA(kh, vh, c, 0, 0, 0);
      c = MFMA(kl, vh, c, 0, 0, 0);
      c = MFMA(kh, vl, c, 0, 0, 0);
    }
#pragma unroll
    for (int r = 0; r < 4; ++r)
      atomicAdd(&ctx[((size_t)(b * 8 + w) * 16 + quad * 4 + r) * 16 + lane16], c[r]);
  }
}

// ---------------- kernel 2: out = (z .* q') @ (ctx_b @ Wo) + bo, M built in-block ----------------
// 512 blocks x 512 thr (8 waves); block = 128 rows, wave w = one 16-row m-tile.
// Replaces old k_mprep + async-staged k_zout: ctx_b (8KB) async16 -> LDS; each thread
// computes 4x8 M values (e-loop order IDENTICAL to old k_mprep -> bit-identical) and
// writes them into mh/ml in the same frag-major permuted layout; then the MFMA loop
// is unchanged. Wo reads are coalesced (oc = p&127 inner) and ctx LDS reads broadcast
// (128-thread groups share (h,d0,e)) -> conflict-free.
__global__ __launch_bounds__(512) void k_zout(
    const unsigned short* __restrict__ qws,
    const float* __restrict__ Wo, const float* __restrict__ ctx,
    const float* __restrict__ bo, const float* __restrict__ ksum,
    float* __restrict__ out) {
  __shared__ __align__(16) unsigned char SM[74240];
  unsigned short* mh = (unsigned short*)SM;            // 16384 shorts (32KB)
  unsigned short* ml = (unsigned short*)(SM + 32768);  // 32KB
  float* ctxS = (float*)(SM + 65536);                  // 2048 f (8KB)
  float* boS  = (float*)(SM + 73728);                  // 128 f
  const int tid = threadIdx.x;
  const int row0 = blockIdx.x * 128;
  const int b = row0 >> 13;
  const int l = tid & 63, w = tid >> 6;
  const int lane16 = l & 15, quad = l >> 4;

  {  // async-stage ctx_b (8KB): wave w copies chunk w*1KB
    const char* gc = (const char*)(ctx + (size_t)b * 2048);
    int off = w * 1024 + l * 16;
    async16(gc + off, (char*)ctxS + off);
  }
  if (tid >= 128 && tid < 256) boS[tid - 128] = bo[tid - 128];

  // A-frags: q' from ws (frag-layout), z in-reg, scale+split — overlapped with staging
  short8 ah[4], al[4];
  {
    int trow = row0 + w * 16 + lane16;      // lane16 = t within the wave's 16-row strip
    const float* kg = ksum + b * 128;
#pragma unroll
    for (int ks = 0; ks < 4; ++ks) {
      union { short8 s8; unsigned short u[8]; } qq;
      qq.s8 = *(const short8*)&qws[(size_t)trow * 128 + ks * 32 + quad * 8];
      int kb = ks * 32 + quad * 8;
      float4 kf0 = *(const float4*)(kg + kb);
      float4 kf1 = *(const float4*)(kg + kb + 4);
      float kf[8] = {kf0.x, kf0.y, kf0.z, kf0.w, kf1.x, kf1.y, kf1.z, kf1.w};
      float s = 0.f;
#pragma unroll
      for (int j = 0; j < 8; ++j) s += bfdec(qq.u[j]) * kf[j];
      s += __shfl_xor(s, 16);        // combine the two 8-halves of the head
      float z = 1.0f / (s + 1e-6f);
      union { short8 s8; unsigned short u[8]; } H, L;
#pragma unroll
      for (int j = 0; j < 8; ++j) splitf(bfdec(qq.u[j]) * z, H.u[j], L.u[j]);
      ah[ks] = H.s8;
      al[ks] = L.s8;
    }
  }
  __syncthreads();                 // ctx_b staged (A-frag prologue hidden under it)

  // build M = ctx_b @ Wo into mh/ml (frag-major permuted layout, as old k_mprep)
#pragma unroll
  for (int pp = 0; pp < 4; ++pp) {
    int p = pp * 512 + tid;        // 2048 (oc,qcg) pairs
    int oc = p & 127, qcg = p >> 7;
    int h = qcg >> 1, d0 = (qcg & 1) * 8;
    const float* C = ctxS + h * 256;   // [d][e]
    float m[8] = {0.f, 0.f, 0.f, 0.f, 0.f, 0.f, 0.f, 0.f};
#pragma unroll 4
    for (int e = 0; e < 16; ++e) {
      float wv = Wo[(size_t)(h * 16 + e) * 128 + oc];
#pragma unroll
      for (int i = 0; i < 8; ++i) m[i] += C[(d0 + i) * 16 + e] * wv;
    }
    union { uint4 q; unsigned short u[8]; } oh, ol;
#pragma unroll
    for (int i = 0; i < 8; ++i) splitf(m[i], oh.u[i], ol.u[i]);
    int grp = (((oc >> 4) * 4 + (qcg >> 2)) * 64) + (qcg & 3) * 16 + (oc & 15);
    *(uint4*)&mh[grp * 8] = oh.q;
    *(uint4*)&ml[grp * 8] = ol.q;
  }
  __syncthreads();                 // M ready in LDS

  floatx4 oacc[8];
#pragma unroll
  for (int i = 0; i < 8; ++i) oacc[i] = (floatx4){0.f, 0.f, 0.f, 0.f};

#pragma unroll
  for (int nt = 0; nt < 8; ++nt) {
#pragma unroll
    for (int ks = 0; ks < 4; ++ks) {
      int moff = ((nt * 4 + ks) * 64 + l) * 8;        // frag-major: lane-contiguous 16B
      short8 wbh = *(const short8*)&mh[moff];
      short8 wbl = *(const short8*)&ml[moff];
      oacc[nt] = MFMA(ah[ks], wbh, oacc[nt], 0, 0, 0);
      oacc[nt] = MFMA(al[ks], wbh, oacc[nt], 0, 0, 0);
      oacc[nt] = MFMA(ah[ks], wbl, oacc[nt], 0, 0, 0);
    }
  }

#pragma unroll
  for (int nt = 0; nt < 8; ++nt) {
    int oc = nt * 16 + lane16;
    float bb = boS[oc];
#pragma unroll
    for (int r = 0; r < 4; ++r) {
      int t = row0 + w * 16 + quad * 4 + r;
      out[(size_t)t * 128 + oc] = oacc[nt][r] + bb;
    }
  }
}

extern "C" void kernel_launch(void* const* d_in, const int* in_sizes, int n_in,
                              void* d_out, int out_size, void* d_ws, size_t ws_size,
                              hipStream_t stream) {
  const float* x  = (const float*)d_in[0];
  const float* Wq = (const float*)d_in[1];
  const float* bq = (const float*)d_in[2];
  const float* Wk = (const float*)d_in[3];
  const float* bk = (const float*)d_in[4];
  const float* Wv = (const float*)d_in[5];
  const float* bv = (const float*)d_in[6];
  const float* Wo = (const float*)d_in[7];
  const float* bo = (const float*)d_in[8];
  float* out = (float*)d_out;

  // ws: qws 16.78MB | WTh 96KB | WTl 96KB | ctx 64KB | ksum 4KB | RC 256KB | RS 256KB
  unsigned short* qws = (unsigned short*)d_ws;         // 65536*128 shorts
  unsigned short* WTh = qws + 8388608;                 // 3 x 16384
  unsigned short* WTl = WTh + 49152;
  float* ctx  = (float*)(WTl + 49152);                 // 16384 f
  float* ksum = ctx + 16384;                           // 1024 f
  float* RC = ksum + 1024;                             // 65536 f
  float* RS = RC + 65536;                              // 65536 f

  k_prep<<<348, 256, 0, stream>>>(Wq, Wk, Wv, WTh, WTl, ctx, RC, RS);
  k_qkv<<<1024, 512, 0, stream>>>(x, WTh, WTl, bq, bk, bv, RC, RS, ctx, ksum, qws);
  k_zout<<<512, 512, 0, stream>>>(qws, Wo, ctx, bo, ksum, out);
}

// Round 11
// 157.192 us; speedup vs baseline: 1.0715x; 1.0103x over previous
//
#include <hip/hip_runtime.h>
#include <hip/hip_bf16.h>

// LightningAttention MI355X — round 19.
// R18 post-mortem: folding k_mprep into k_zout was NEUTRAL (-0.2us) -> dispatch gaps are
//   small; the residual lives inside kernel execution. Fusion line closed.
// R19 theory — k_qkv completion tail: 120 regs (72V+48A) -> 4 waves/SIMD -> 2 blocks/CU
//   (register-limited, NOT the assumed LDS-4). Theoretical occupancy 50%; measured 19%.
//   Signature of a drain tail: the last thing each wave does is 4 atomicAdds into a 16KB
//   ctx region (2.1M RMWs, ~8K serialized per cache line at TCC); waves can't retire
//   until RMWs complete. FIX (single variable): issue ctx/ksum atomics BEFORE the q-side
//   epilogue (rope(q) + bfh + 16 qws stores) so the drain overlaps real work.
//   Order: bias -> rope(k) -> ksum atomic -> xpose(k,v)+ctx MFMA+ctx atomics
//          -> rope(q) -> qws stores.
// k_prep / k_zout identical to R18. 3 dispatches.
// B=8 T=8192 DM=128 H=8 Dh=16. Split-bf16 (hi+lo) on all MFMA surfaces except q' (bf16).

typedef __attribute__((ext_vector_type(8))) short short8;   // 8 bf16 (MFMA A/B frag)
typedef __attribute__((ext_vector_type(4))) float floatx4;  // MFMA C/D frag

#define DEV __device__ __forceinline__
#define MFMA __builtin_amdgcn_mfma_f32_16x16x32_bf16

#define XPAD 136   // x-tile row stride in shorts. 136 -> LDS 39424B. Do not grow.

DEV unsigned short bfh(float f) {
  unsigned int x = __float_as_uint(f);
  x += 0x7fffu + ((x >> 16) & 1u);     // RNE
  return (unsigned short)(x >> 16);
}
DEV float bfdec(unsigned short u) { return __uint_as_float(((unsigned int)u) << 16); }
DEV void splitf(float f, unsigned short& h, unsigned short& l) {
  h = bfh(f);
  l = bfh(f - bfdec(h));
}
DEV void split8(const float* p, short8& h8, short8& l8) {
  float4 a = *(const float4*)p;
  float4 b = *(const float4*)(p + 4);
  float v[8] = {a.x, a.y, a.z, a.w, b.x, b.y, b.z, b.w};
  union { short8 s; unsigned short u[8]; } H, L;
#pragma unroll
  for (int i = 0; i < 8; ++i) splitf(v[i], H.u[i], L.u[i]);
  h8 = H.s; l8 = L.s;
}

// Register transpose (verified R5-R7): C-layout tile val(n=lane16, m=mt*16+quad*4+r),
// rows m0/m1 -> split frag F[lane16][k=quad*8+j] over the 32-wide m-window.
DEV void xpose_frag(floatx4 m0, floatx4 m1, int lane16, int quad,
                    short8& hi, short8& lo) {
  union { short8 s; unsigned short u[8]; } H, L;
#pragma unroll
  for (int j = 0; j < 8; ++j) {
    int srcLane = lane16 + (((quad & 1) * 2 + (j >> 2)) << 4);
    float vA = __shfl(m0[j & 3], srcLane, 64);
    float vB = __shfl(m1[j & 3], srcLane, 64);
    float v = (quad < 2) ? vA : vB;
    splitf(v, H.u[j], L.u[j]);
  }
  hi = H.s; lo = L.s;
}

// async 16B global->LDS (per-lane gsrc; LDS dest must be wave-uniform base + lane*16)
DEV void async16(const void* g, void* l) {
  __builtin_amdgcn_global_load_lds(
      (const __attribute__((address_space(1))) unsigned int*)g,
      (__attribute__((address_space(3))) unsigned int*)l, 16, 0, 0);
}

// ---------------- k_prep: Wq/Wk/Wv split-transpose + zero ctx/ksum + rope table ----------------
__global__ void k_prep(const float* __restrict__ Wq, const float* __restrict__ Wk,
                       const float* __restrict__ Wv,
                       unsigned short* __restrict__ WTh, unsigned short* __restrict__ WTl,
                       float* __restrict__ ctxz,
                       float* __restrict__ RC, float* __restrict__ RS) {
  int gid = blockIdx.x * 256 + threadIdx.x;
  if (gid < 6144) {               // 3 mats x 128 n x 16 k-groups of 8
    int mat = gid >> 11, r = gid & 2047, n = r >> 4, k0 = (r & 15) * 8;
    const float* W = (mat == 0) ? Wq : (mat == 1) ? Wk : Wv;
    union { uint4 q; unsigned short u[8]; } oh, ol;
#pragma unroll
    for (int i = 0; i < 8; ++i) splitf(W[(size_t)(k0 + i) * 128 + n], oh.u[i], ol.u[i]);
    *(uint4*)&WTh[mat * 16384 + n * 128 + k0] = oh.q;
    *(uint4*)&WTl[mat * 16384 + n * 128 + k0] = ol.q;
  } else if (gid < 6144 + 17408) {
    ctxz[gid - 6144] = 0.0f;      // ctx (16384) + ksum (1024)
  } else if (gid < 23552 + 65536) {
    int idx = gid - 23552;        // t*8 + j, T=8192
    int t = idx >> 3, j = idx & 7;
    float invf = 1.0f / powf(10000.0f, (float)j * 0.125f);
    float s, c;
    sincosf((float)t * invf, &s, &c);
    RC[idx] = c; RS[idx] = s;     // bit-identical to the old per-block computation
  }
}

// ---------------- kernel 1: qkv GEMM + rope/elu + q'/ksum/ctx. 512 thr, wave=1 head ----------------
__global__ __launch_bounds__(512) void k_qkv(
    const float* __restrict__ x,
    const unsigned short* __restrict__ WTh, const unsigned short* __restrict__ WTl,
    const float* __restrict__ bq, const float* __restrict__ bk, const float* __restrict__ bv,
    const float* __restrict__ RC, const float* __restrict__ RS,
    float* __restrict__ ctx, float* __restrict__ ksum,
    unsigned short* __restrict__ qws) {
  __shared__ unsigned short xh[64 * XPAD], xl[64 * XPAD];   // pre-split x tile [row][k]
  __shared__ float rc[64][9], rs[64][9];
  const int tid = threadIdx.x;
  const int row0 = blockIdx.x * 64;
  const int b = row0 >> 13;
  const int t0 = row0 & 8191;

  {  // rope table: coalesced load from precomputed global table (no trig)
    int r = tid >> 3, j = tid & 7;
    int idx = (t0 + r) * 8 + j;
    rc[r][j] = RC[idx];
    rs[r][j] = RS[idx];
  }
  {  // stage x, split ONCE per element
    int r = tid >> 3, cg = (tid & 7) * 16;
    const float* xp = x + (size_t)(row0 + r) * 128 + cg;
    short8 h0, l0, h1, l1;
    split8(xp, h0, l0);
    split8(xp + 8, h1, l1);
    *(short8*)&xh[r * XPAD + cg] = h0;
    *(short8*)&xh[r * XPAD + cg + 8] = h1;
    *(short8*)&xl[r * XPAD + cg] = l0;
    *(short8*)&xl[r * XPAD + cg + 8] = l1;
  }
  __syncthreads();                 // only barrier

  const int l = tid & 63, w = tid >> 6;       // wave w owns head w
  const int lane16 = l & 15, quad = l >> 4;

  floatx4 acc[3][4];               // [mat: q,k,v][mt]  = 48 AGPRs
#pragma unroll
  for (int i = 0; i < 3; ++i)
#pragma unroll
    for (int j = 0; j < 4; ++j) acc[i][j] = (floatx4){0.f, 0.f, 0.f, 0.f};

  // weight base offsets per mat (ks advances by +32 shorts)
  size_t wbase[3];
#pragma unroll
  for (int mat = 0; mat < 3; ++mat)
    wbase[mat] = (size_t)mat * 16384 + (size_t)(w * 16 + lane16) * 128 + quad * 8;

  // double-buffered weight frags: prefetch ks+1 while computing ks
  short8 wh[2][3], wl[2][3];
#pragma unroll
  for (int mat = 0; mat < 3; ++mat) {
    wh[0][mat] = *(const short8*)(WTh + wbase[mat]);
    wl[0][mat] = *(const short8*)(WTl + wbase[mat]);
  }

#pragma unroll
  for (int ks = 0; ks < 4; ++ks) {
    const int cur = ks & 1, nxt = cur ^ 1;
    if (ks < 3) {
#pragma unroll
      for (int mat = 0; mat < 3; ++mat) {
        wh[nxt][mat] = *(const short8*)(WTh + wbase[mat] + (ks + 1) * 32);
        wl[nxt][mat] = *(const short8*)(WTl + wbase[mat] + (ks + 1) * 32);
      }
    }
    short8 afh[4], afl[4];
#pragma unroll
    for (int mt = 0; mt < 4; ++mt) {
      int off = (mt * 16 + lane16) * XPAD + ks * 32 + quad * 8;
      afh[mt] = *(const short8*)&xh[off];
      afl[mt] = *(const short8*)&xl[off];
    }
#pragma unroll
    for (int mat = 0; mat < 3; ++mat) {
#pragma unroll
      for (int mt = 0; mt < 4; ++mt) {
        acc[mat][mt] = MFMA(afh[mt], wh[cur][mat], acc[mat][mt], 0, 0, 0);
        acc[mat][mt] = MFMA(afl[mt], wh[cur][mat], acc[mat][mt], 0, 0, 0);
        acc[mat][mt] = MFMA(afh[mt], wl[cur][mat], acc[mat][mt], 0, 0, 0);
      }
    }
  }

  // bias (lane16 = col within head)
  {
    int col = w * 16 + lane16;
    float bias[3] = {bq[col], bk[col], bv[col]};
#pragma unroll
    for (int mat = 0; mat < 3; ++mat)
#pragma unroll
      for (int mt = 0; mt < 4; ++mt)
#pragma unroll
        for (int r = 0; r < 4; ++r) acc[mat][mt][r] += bias[mat];
  }

  const int d = lane16, jj = d & 7;

  // rope + elu+1 on K (mat 1) only — K/V-side results feed the atomics, issue them first
  {
#pragma unroll
    for (int mt = 0; mt < 4; ++mt) {
#pragma unroll
      for (int r = 0; r < 4; ++r) {
        int tl = mt * 16 + quad * 4 + r;
        float cc = rc[tl][jj], ss = rs[tl][jj];
        float v = acc[1][mt][r];
        float p = __shfl_xor(v, 8);          // pair (d, d+8)
        float nv = (d < 8) ? (v * cc - p * ss) : (p * ss + v * cc);
        acc[1][mt][r] = (nv > 0.f) ? (nv + 1.f) : __expf(nv);
      }
    }
  }

  // ksum[h=w][d] from k — atomic issued early
  {
    float s = 0.f;
#pragma unroll
    for (int mt = 0; mt < 4; ++mt)
#pragma unroll
      for (int r = 0; r < 4; ++r) s += acc[1][mt][r];
    s += __shfl_xor(s, 16);
    s += __shfl_xor(s, 32);
    if (l < 16) atomicAdd(&ksum[(b * 8 + w) * 16 + lane16], s);
  }

  // ctx[h=w] += K^T V via register transposes — atomics issued early; their TCC drain
  // overlaps the q-side epilogue below.
  {
    floatx4 c = (floatx4){0.f, 0.f, 0.f, 0.f};
#pragma unroll
    for (int ks2 = 0; ks2 < 2; ++ks2) {
      short8 kh, kl, vh, vl;
      xpose_frag(acc[1][ks2 * 2], acc[1][ks2 * 2 + 1], lane16, quad, kh, kl);
      xpose_frag(acc[2][ks2 * 2], acc[2][ks2 * 2 + 1], lane16, quad, vh, vl);
      c = MFMA(kh, vh, c, 0, 0, 0);
      c = MFMA(kl, vh, c, 0, 0, 0);
      c = MFMA(kh, vl, c, 0, 0, 0);
    }
#pragma unroll
    for (int r = 0; r < 4; ++r)
      atomicAdd(&ctx[((size_t)(b * 8 + w) * 16 + quad * 4 + r) * 16 + lane16], c[r]);
  }

  // rope + elu+1 on Q (mat 0) + q' stores — overlaps the atomic drain
  {
#pragma unroll
    for (int mt = 0; mt < 4; ++mt) {
#pragma unroll
      for (int r = 0; r < 4; ++r) {
        int tl = mt * 16 + quad * 4 + r;
        float cc = rc[tl][jj], ss = rs[tl][jj];
        float v = acc[0][mt][r];
        float p = __shfl_xor(v, 8);          // pair (d, d+8)
        float nv = (d < 8) ? (v * cc - p * ss) : (p * ss + v * cc);
        acc[0][mt][r] = (nv > 0.f) ? (nv + 1.f) : __expf(nv);
      }
    }
#pragma unroll
    for (int mt = 0; mt < 4; ++mt)
#pragma unroll
      for (int r = 0; r < 4; ++r)
        qws[(size_t)(row0 + mt * 16 + quad * 4 + r) * 128 + w * 16 + lane16] =
            bfh(acc[0][mt][r]);
  }
}

// ---------------- kernel 2: out = (z .* q') @ (ctx_b @ Wo) + bo, M built in-block ----------------
// 512 blocks x 512 thr (8 waves); block = 128 rows, wave w = one 16-row m-tile.
__global__ __launch_bounds__(512) void k_zout(
    const unsigned short* __restrict__ qws,
    const float* __restrict__ Wo, const float* __restrict__ ctx,
    const float* __restrict__ bo, const float* __restrict__ ksum,
    float* __restrict__ out) {
  __shared__ __align__(16) unsigned char SM[74240];
  unsigned short* mh = (unsigned short*)SM;            // 16384 shorts (32KB)
  unsigned short* ml = (unsigned short*)(SM + 32768);  // 32KB
  float* ctxS = (float*)(SM + 65536);                  // 2048 f (8KB)
  float* boS  = (float*)(SM + 73728);                  // 128 f
  const int tid = threadIdx.x;
  const int row0 = blockIdx.x * 128;
  const int b = row0 >> 13;
  const int l = tid & 63, w = tid >> 6;
  const int lane16 = l & 15, quad = l >> 4;

  {  // async-stage ctx_b (8KB): wave w copies chunk w*1KB
    const char* gc = (const char*)(ctx + (size_t)b * 2048);
    int off = w * 1024 + l * 16;
    async16(gc + off, (char*)ctxS + off);
  }
  if (tid >= 128 && tid < 256) boS[tid - 128] = bo[tid - 128];

  // A-frags: q' from ws (frag-layout), z in-reg, scale+split — overlapped with staging
  short8 ah[4], al[4];
  {
    int trow = row0 + w * 16 + lane16;      // lane16 = t within the wave's 16-row strip
    const float* kg = ksum + b * 128;
#pragma unroll
    for (int ks = 0; ks < 4; ++ks) {
      union { short8 s8; unsigned short u[8]; } qq;
      qq.s8 = *(const short8*)&qws[(size_t)trow * 128 + ks * 32 + quad * 8];
      int kb = ks * 32 + quad * 8;
      float4 kf0 = *(const float4*)(kg + kb);
      float4 kf1 = *(const float4*)(kg + kb + 4);
      float kf[8] = {kf0.x, kf0.y, kf0.z, kf0.w, kf1.x, kf1.y, kf1.z, kf1.w};
      float s = 0.f;
#pragma unroll
      for (int j = 0; j < 8; ++j) s += bfdec(qq.u[j]) * kf[j];
      s += __shfl_xor(s, 16);        // combine the two 8-halves of the head
      float z = 1.0f / (s + 1e-6f);
      union { short8 s8; unsigned short u[8]; } H, L;
#pragma unroll
      for (int j = 0; j < 8; ++j) splitf(bfdec(qq.u[j]) * z, H.u[j], L.u[j]);
      ah[ks] = H.s8;
      al[ks] = L.s8;
    }
  }
  __syncthreads();                 // ctx_b staged (A-frag prologue hidden under it)

  // build M = ctx_b @ Wo into mh/ml (frag-major permuted layout; e-loop order = k_mprep)
#pragma unroll
  for (int pp = 0; pp < 4; ++pp) {
    int p = pp * 512 + tid;        // 2048 (oc,qcg) pairs
    int oc = p & 127, qcg = p >> 7;
    int h = qcg >> 1, d0 = (qcg & 1) * 8;
    const float* C = ctxS + h * 256;   // [d][e]
    float m[8] = {0.f, 0.f, 0.f, 0.f, 0.f, 0.f, 0.f, 0.f};
#pragma unroll 4
    for (int e = 0; e < 16; ++e) {
      float wv = Wo[(size_t)(h * 16 + e) * 128 + oc];
#pragma unroll
      for (int i = 0; i < 8; ++i) m[i] += C[(d0 + i) * 16 + e] * wv;
    }
    union { uint4 q; unsigned short u[8]; } oh, ol;
#pragma unroll
    for (int i = 0; i < 8; ++i) splitf(m[i], oh.u[i], ol.u[i]);
    int grp = (((oc >> 4) * 4 + (qcg >> 2)) * 64) + (qcg & 3) * 16 + (oc & 15);
    *(uint4*)&mh[grp * 8] = oh.q;
    *(uint4*)&ml[grp * 8] = ol.q;
  }
  __syncthreads();                 // M ready in LDS

  floatx4 oacc[8];
#pragma unroll
  for (int i = 0; i < 8; ++i) oacc[i] = (floatx4){0.f, 0.f, 0.f, 0.f};

#pragma unroll
  for (int nt = 0; nt < 8; ++nt) {
#pragma unroll
    for (int ks = 0; ks < 4; ++ks) {
      int moff = ((nt * 4 + ks) * 64 + l) * 8;        // frag-major: lane-contiguous 16B
      short8 wbh = *(const short8*)&mh[moff];
      short8 wbl = *(const short8*)&ml[moff];
      oacc[nt] = MFMA(ah[ks], wbh, oacc[nt], 0, 0, 0);
      oacc[nt] = MFMA(al[ks], wbh, oacc[nt], 0, 0, 0);
      oacc[nt] = MFMA(ah[ks], wbl, oacc[nt], 0, 0, 0);
    }
  }

#pragma unroll
  for (int nt = 0; nt < 8; ++nt) {
    int oc = nt * 16 + lane16;
    float bb = boS[oc];
#pragma unroll
    for (int r = 0; r < 4; ++r) {
      int t = row0 + w * 16 + quad * 4 + r;
      out[(size_t)t * 128 + oc] = oacc[nt][r] + bb;
    }
  }
}

extern "C" void kernel_launch(void* const* d_in, const int* in_sizes, int n_in,
                              void* d_out, int out_size, void* d_ws, size_t ws_size,
                              hipStream_t stream) {
  const float* x  = (const float*)d_in[0];
  const float* Wq = (const float*)d_in[1];
  const float* bq = (const float*)d_in[2];
  const float* Wk = (const float*)d_in[3];
  const float* bk = (const float*)d_in[4];
  const float* Wv = (const float*)d_in[5];
  const float* bv = (const float*)d_in[6];
  const float* Wo = (const float*)d_in[7];
  const float* bo = (const float*)d_in[8];
  float* out = (float*)d_out;

  // ws: qws 16.78MB | WTh 96KB | WTl 96KB | ctx 64KB | ksum 4KB | RC 256KB | RS 256KB
  unsigned short* qws = (unsigned short*)d_ws;         // 65536*128 shorts
  unsigned short* WTh = qws + 8388608;                 // 3 x 16384
  unsigned short* WTl = WTh + 49152;
  float* ctx  = (float*)(WTl + 49152);                 // 16384 f
  float* ksum = ctx + 16384;                           // 1024 f
  float* RC = ksum + 1024;                             // 65536 f
  float* RS = RC + 65536;                              // 65536 f

  k_prep<<<348, 256, 0, stream>>>(Wq, Wk, Wv, WTh, WTl, ctx, RC, RS);
  k_qkv<<<1024, 512, 0, stream>>>(x, WTh, WTl, bq, bk, bv, RC, RS, ctx, ksum, qws);
  k_zout<<<512, 512, 0, stream>>>(qws, Wo, ctx, bo, ksum, out);
}

// Round 12
// 153.999 us; speedup vs baseline: 1.0937x; 1.0207x over previous
//
#include <hip/hip_runtime.h>
#include <hip/hip_bf16.h>

// LightningAttention MI355X — round 20.
// R19 (+2us: atomic-early reorder) extended: k_qkv 2-tile software pipeline.
//   512 blocks x 512 thr; block = 128 rows = 2 x 64-row tiles.
//   Order: stage0 | bar | GEMM0 | stage1 | bar | epi0 | GEMM1 | epi1.
//   - tile1 staging amortizes one prologue per 128 rows (was per 64);
//   - epi0's ctx/ksum atomics + qws stores drain under GEMM1's 48 MFMA + 32 ds_read
//     (much bigger shadow than R19's rope-q tail);
//   - only epi1's atomics exposed at block end (halves exposed tails).
//   LDS 78848B (2 x-tile dbuf + 128-row rope) -> still 2 blocks/CU; no new cross-GEMM
//   register state (stays ~116 < 128-reg cliff).
// k_prep / k_zout identical to R19. 3 dispatches.
// B=8 T=8192 DM=128 H=8 Dh=16. Split-bf16 (hi+lo) on all MFMA surfaces except q' (bf16).

typedef __attribute__((ext_vector_type(8))) short short8;   // 8 bf16 (MFMA A/B frag)
typedef __attribute__((ext_vector_type(4))) float floatx4;  // MFMA C/D frag

#define DEV __device__ __forceinline__
#define MFMA __builtin_amdgcn_mfma_f32_16x16x32_bf16

#define XPAD 136   // x-tile row stride in shorts (17x16B slots)

DEV unsigned short bfh(float f) {
  unsigned int x = __float_as_uint(f);
  x += 0x7fffu + ((x >> 16) & 1u);     // RNE
  return (unsigned short)(x >> 16);
}
DEV float bfdec(unsigned short u) { return __uint_as_float(((unsigned int)u) << 16); }
DEV void splitf(float f, unsigned short& h, unsigned short& l) {
  h = bfh(f);
  l = bfh(f - bfdec(h));
}
DEV void split8(const float* p, short8& h8, short8& l8) {
  float4 a = *(const float4*)p;
  float4 b = *(const float4*)(p + 4);
  float v[8] = {a.x, a.y, a.z, a.w, b.x, b.y, b.z, b.w};
  union { short8 s; unsigned short u[8]; } H, L;
#pragma unroll
  for (int i = 0; i < 8; ++i) splitf(v[i], H.u[i], L.u[i]);
  h8 = H.s; l8 = L.s;
}

// Register transpose (verified R5-R7): C-layout tile val(n=lane16, m=mt*16+quad*4+r),
// rows m0/m1 -> split frag F[lane16][k=quad*8+j] over the 32-wide m-window.
DEV void xpose_frag(floatx4 m0, floatx4 m1, int lane16, int quad,
                    short8& hi, short8& lo) {
  union { short8 s; unsigned short u[8]; } H, L;
#pragma unroll
  for (int j = 0; j < 8; ++j) {
    int srcLane = lane16 + (((quad & 1) * 2 + (j >> 2)) << 4);
    float vA = __shfl(m0[j & 3], srcLane, 64);
    float vB = __shfl(m1[j & 3], srcLane, 64);
    float v = (quad < 2) ? vA : vB;
    splitf(v, H.u[j], L.u[j]);
  }
  hi = H.s; lo = L.s;
}

// async 16B global->LDS (per-lane gsrc; LDS dest must be wave-uniform base + lane*16)
DEV void async16(const void* g, void* l) {
  __builtin_amdgcn_global_load_lds(
      (const __attribute__((address_space(1))) unsigned int*)g,
      (__attribute__((address_space(3))) unsigned int*)l, 16, 0, 0);
}

// One 64-row GEMM tile: acc[mat][mt] = x_tile @ {Wq,Wk,Wv} (split-bf16, 48 MFMAs)
DEV void gemm_tile(const unsigned short* __restrict__ xh, const unsigned short* __restrict__ xl,
                   const unsigned short* __restrict__ WTh, const unsigned short* __restrict__ WTl,
                   const size_t* wbase, int lane16, int quad, floatx4 (&acc)[3][4]) {
#pragma unroll
  for (int i = 0; i < 3; ++i)
#pragma unroll
    for (int j = 0; j < 4; ++j) acc[i][j] = (floatx4){0.f, 0.f, 0.f, 0.f};

  short8 wh[2][3], wl[2][3];       // double-buffered weight frags
#pragma unroll
  for (int mat = 0; mat < 3; ++mat) {
    wh[0][mat] = *(const short8*)(WTh + wbase[mat]);
    wl[0][mat] = *(const short8*)(WTl + wbase[mat]);
  }
#pragma unroll
  for (int ks = 0; ks < 4; ++ks) {
    const int cur = ks & 1, nxt = cur ^ 1;
    if (ks < 3) {
#pragma unroll
      for (int mat = 0; mat < 3; ++mat) {
        wh[nxt][mat] = *(const short8*)(WTh + wbase[mat] + (ks + 1) * 32);
        wl[nxt][mat] = *(const short8*)(WTl + wbase[mat] + (ks + 1) * 32);
      }
    }
    short8 afh[4], afl[4];
#pragma unroll
    for (int mt = 0; mt < 4; ++mt) {
      int off = (mt * 16 + lane16) * XPAD + ks * 32 + quad * 8;
      afh[mt] = *(const short8*)&xh[off];
      afl[mt] = *(const short8*)&xl[off];
    }
#pragma unroll
    for (int mat = 0; mat < 3; ++mat) {
#pragma unroll
      for (int mt = 0; mt < 4; ++mt) {
        acc[mat][mt] = MFMA(afh[mt], wh[cur][mat], acc[mat][mt], 0, 0, 0);
        acc[mat][mt] = MFMA(afl[mt], wh[cur][mat], acc[mat][mt], 0, 0, 0);
        acc[mat][mt] = MFMA(afh[mt], wl[cur][mat], acc[mat][mt], 0, 0, 0);
      }
    }
  }
}

// Epilogue for one tile (R19 order: K-side + atomics first, q-side last).
// trow0 = global row of tile start; rc/rs indexed with tile-local row + roff.
DEV void epilogue_tile(floatx4 (&acc)[3][4], const float (*rc)[9], const float (*rs)[9],
                       int roff, int trow0, int b, int w, int lane16, int quad, int l,
                       const float* bq, const float* bk, const float* bv,
                       float* __restrict__ ctx, float* __restrict__ ksum,
                       unsigned short* __restrict__ qws) {
  {  // bias
    int col = w * 16 + lane16;
    float bias[3] = {bq[col], bk[col], bv[col]};
#pragma unroll
    for (int mat = 0; mat < 3; ++mat)
#pragma unroll
      for (int mt = 0; mt < 4; ++mt)
#pragma unroll
        for (int r = 0; r < 4; ++r) acc[mat][mt][r] += bias[mat];
  }
  const int d = lane16, jj = d & 7;

  // rope + elu+1 on K first (feeds the atomics)
#pragma unroll
  for (int mt = 0; mt < 4; ++mt) {
#pragma unroll
    for (int r = 0; r < 4; ++r) {
      int tl = roff + mt * 16 + quad * 4 + r;
      float cc = rc[tl][jj], ss = rs[tl][jj];
      float v = acc[1][mt][r];
      float p = __shfl_xor(v, 8);          // pair (d, d+8)
      float nv = (d < 8) ? (v * cc - p * ss) : (p * ss + v * cc);
      acc[1][mt][r] = (nv > 0.f) ? (nv + 1.f) : __expf(nv);
    }
  }
  {  // ksum atomic — issued early
    float s = 0.f;
#pragma unroll
    for (int mt = 0; mt < 4; ++mt)
#pragma unroll
      for (int r = 0; r < 4; ++r) s += acc[1][mt][r];
    s += __shfl_xor(s, 16);
    s += __shfl_xor(s, 32);
    if (l < 16) atomicAdd(&ksum[(b * 8 + w) * 16 + lane16], s);
  }
  {  // ctx += K^T V — atomics issued early; drain overlaps following work
    floatx4 c = (floatx4){0.f, 0.f, 0.f, 0.f};
#pragma unroll
    for (int ks2 = 0; ks2 < 2; ++ks2) {
      short8 kh, kl, vh, vl;
      xpose_frag(acc[1][ks2 * 2], acc[1][ks2 * 2 + 1], lane16, quad, kh, kl);
      xpose_frag(acc[2][ks2 * 2], acc[2][ks2 * 2 + 1], lane16, quad, vh, vl);
      c = MFMA(kh, vh, c, 0, 0, 0);
      c = MFMA(kl, vh, c, 0, 0, 0);
      c = MFMA(kh, vl, c, 0, 0, 0);
    }
#pragma unroll
    for (int r = 0; r < 4; ++r)
      atomicAdd(&ctx[((size_t)(b * 8 + w) * 16 + quad * 4 + r) * 16 + lane16], c[r]);
  }
  // rope + elu+1 on Q + q' stores (drains under next tile's GEMM)
#pragma unroll
  for (int mt = 0; mt < 4; ++mt) {
#pragma unroll
    for (int r = 0; r < 4; ++r) {
      int tl = roff + mt * 16 + quad * 4 + r;
      float cc = rc[tl][jj], ss = rs[tl][jj];
      float v = acc[0][mt][r];
      float p = __shfl_xor(v, 8);          // pair (d, d+8)
      float nv = (d < 8) ? (v * cc - p * ss) : (p * ss + v * cc);
      acc[0][mt][r] = (nv > 0.f) ? (nv + 1.f) : __expf(nv);
    }
  }
#pragma unroll
  for (int mt = 0; mt < 4; ++mt)
#pragma unroll
    for (int r = 0; r < 4; ++r)
      qws[(size_t)(trow0 + mt * 16 + quad * 4 + r) * 128 + w * 16 + lane16] =
          bfh(acc[0][mt][r]);
}

// ---------------- k_prep: Wq/Wk/Wv split-transpose + zero ctx/ksum + rope table ----------------
__global__ void k_prep(const float* __restrict__ Wq, const float* __restrict__ Wk,
                       const float* __restrict__ Wv,
                       unsigned short* __restrict__ WTh, unsigned short* __restrict__ WTl,
                       float* __restrict__ ctxz,
                       float* __restrict__ RC, float* __restrict__ RS) {
  int gid = blockIdx.x * 256 + threadIdx.x;
  if (gid < 6144) {               // 3 mats x 128 n x 16 k-groups of 8
    int mat = gid >> 11, r = gid & 2047, n = r >> 4, k0 = (r & 15) * 8;
    const float* W = (mat == 0) ? Wq : (mat == 1) ? Wk : Wv;
    union { uint4 q; unsigned short u[8]; } oh, ol;
#pragma unroll
    for (int i = 0; i < 8; ++i) splitf(W[(size_t)(k0 + i) * 128 + n], oh.u[i], ol.u[i]);
    *(uint4*)&WTh[mat * 16384 + n * 128 + k0] = oh.q;
    *(uint4*)&WTl[mat * 16384 + n * 128 + k0] = ol.q;
  } else if (gid < 6144 + 17408) {
    ctxz[gid - 6144] = 0.0f;      // ctx (16384) + ksum (1024)
  } else if (gid < 23552 + 65536) {
    int idx = gid - 23552;        // t*8 + j, T=8192
    int t = idx >> 3, j = idx & 7;
    float invf = 1.0f / powf(10000.0f, (float)j * 0.125f);
    float s, c;
    sincosf((float)t * invf, &s, &c);
    RC[idx] = c; RS[idx] = s;     // bit-identical to the old per-block computation
  }
}

// ---------------- kernel 1: qkv, 2-tile pipelined. 512 blocks x 512 thr ----------------
__global__ __launch_bounds__(512) void k_qkv(
    const float* __restrict__ x,
    const unsigned short* __restrict__ WTh, const unsigned short* __restrict__ WTl,
    const float* __restrict__ bq, const float* __restrict__ bk, const float* __restrict__ bv,
    const float* __restrict__ RC, const float* __restrict__ RS,
    float* __restrict__ ctx, float* __restrict__ ksum,
    unsigned short* __restrict__ qws) {
  __shared__ unsigned short xh[2][64 * XPAD], xl[2][64 * XPAD];  // 69632B dbuf
  __shared__ float rc[128][9], rs[128][9];                        // 9216B
  const int tid = threadIdx.x;
  const int row0 = blockIdx.x * 128;
  const int b = row0 >> 13;     // 128 | 8192 -> constant across both tiles
  const int t0 = row0 & 8191;

  {  // rope table for all 128 rows: 512 threads x 2
#pragma unroll
    for (int it = 0; it < 2; ++it) {
      int ii = it * 512 + tid;
      int r = ii >> 3, j = ii & 7;
      int idx = (t0 + r) * 8 + j;
      rc[r][j] = RC[idx];
      rs[r][j] = RS[idx];
    }
  }
  {  // stage tile 0
    int r = tid >> 3, cg = (tid & 7) * 16;
    const float* xp = x + (size_t)(row0 + r) * 128 + cg;
    short8 h0, l0, h1, l1;
    split8(xp, h0, l0);
    split8(xp + 8, h1, l1);
    *(short8*)&xh[0][r * XPAD + cg] = h0;
    *(short8*)&xh[0][r * XPAD + cg + 8] = h1;
    *(short8*)&xl[0][r * XPAD + cg] = l0;
    *(short8*)&xl[0][r * XPAD + cg + 8] = l1;
  }
  __syncthreads();

  const int l = tid & 63, w = tid >> 6;       // wave w owns head w
  const int lane16 = l & 15, quad = l >> 4;

  size_t wbase[3];
#pragma unroll
  for (int mat = 0; mat < 3; ++mat)
    wbase[mat] = (size_t)mat * 16384 + (size_t)(w * 16 + lane16) * 128 + quad * 8;

  floatx4 acc[3][4];               // 48 AGPRs

  // ---- tile 0 GEMM ----
  gemm_tile(xh[0], xl[0], WTh, WTl, wbase, lane16, quad, acc);

  // ---- stage tile 1 (overlaps other block; split+write hidden by epi0 below) ----
  {
    int r = tid >> 3, cg = (tid & 7) * 16;
    const float* xp = x + (size_t)(row0 + 64 + r) * 128 + cg;
    short8 h0, l0, h1, l1;
    split8(xp, h0, l0);
    split8(xp + 8, h1, l1);
    *(short8*)&xh[1][r * XPAD + cg] = h0;
    *(short8*)&xh[1][r * XPAD + cg + 8] = h1;
    *(short8*)&xl[1][r * XPAD + cg] = l0;
    *(short8*)&xl[1][r * XPAD + cg + 8] = l1;
  }
  __syncthreads();

  // ---- tile 0 epilogue (atomics early; stores drain under tile-1 GEMM) ----
  epilogue_tile(acc, rc, rs, 0, row0, b, w, lane16, quad, l,
                bq, bk, bv, ctx, ksum, qws);

  // ---- tile 1 GEMM + epilogue ----
  gemm_tile(xh[1], xl[1], WTh, WTl, wbase, lane16, quad, acc);
  epilogue_tile(acc, rc, rs, 64, row0 + 64, b, w, lane16, quad, l,
                bq, bk, bv, ctx, ksum, qws);
}

// ---------------- kernel 2: out = (z .* q') @ (ctx_b @ Wo) + bo, M built in-block ----------------
// 512 blocks x 512 thr (8 waves); block = 128 rows, wave w = one 16-row m-tile.
__global__ __launch_bounds__(512) void k_zout(
    const unsigned short* __restrict__ qws,
    const float* __restrict__ Wo, const float* __restrict__ ctx,
    const float* __restrict__ bo, const float* __restrict__ ksum,
    float* __restrict__ out) {
  __shared__ __align__(16) unsigned char SM[74240];
  unsigned short* mh = (unsigned short*)SM;            // 16384 shorts (32KB)
  unsigned short* ml = (unsigned short*)(SM + 32768);  // 32KB
  float* ctxS = (float*)(SM + 65536);                  // 2048 f (8KB)
  float* boS  = (float*)(SM + 73728);                  // 128 f
  const int tid = threadIdx.x;
  const int row0 = blockIdx.x * 128;
  const int b = row0 >> 13;
  const int l = tid & 63, w = tid >> 6;
  const int lane16 = l & 15, quad = l >> 4;

  {  // async-stage ctx_b (8KB): wave w copies chunk w*1KB
    const char* gc = (const char*)(ctx + (size_t)b * 2048);
    int off = w * 1024 + l * 16;
    async16(gc + off, (char*)ctxS + off);
  }
  if (tid >= 128 && tid < 256) boS[tid - 128] = bo[tid - 128];

  // A-frags: q' from ws (frag-layout), z in-reg, scale+split — overlapped with staging
  short8 ah[4], al[4];
  {
    int trow = row0 + w * 16 + lane16;      // lane16 = t within the wave's 16-row strip
    const float* kg = ksum + b * 128;
#pragma unroll
    for (int ks = 0; ks < 4; ++ks) {
      union { short8 s8; unsigned short u[8]; } qq;
      qq.s8 = *(const short8*)&qws[(size_t)trow * 128 + ks * 32 + quad * 8];
      int kb = ks * 32 + quad * 8;
      float4 kf0 = *(const float4*)(kg + kb);
      float4 kf1 = *(const float4*)(kg + kb + 4);
      float kf[8] = {kf0.x, kf0.y, kf0.z, kf0.w, kf1.x, kf1.y, kf1.z, kf1.w};
      float s = 0.f;
#pragma unroll
      for (int j = 0; j < 8; ++j) s += bfdec(qq.u[j]) * kf[j];
      s += __shfl_xor(s, 16);        // combine the two 8-halves of the head
      float z = 1.0f / (s + 1e-6f);
      union { short8 s8; unsigned short u[8]; } H, L;
#pragma unroll
      for (int j = 0; j < 8; ++j) splitf(bfdec(qq.u[j]) * z, H.u[j], L.u[j]);
      ah[ks] = H.s8;
      al[ks] = L.s8;
    }
  }
  __syncthreads();                 // ctx_b staged (A-frag prologue hidden under it)

  // build M = ctx_b @ Wo into mh/ml (frag-major permuted layout; e-loop order = k_mprep)
#pragma unroll
  for (int pp = 0; pp < 4; ++pp) {
    int p = pp * 512 + tid;        // 2048 (oc,qcg) pairs
    int oc = p & 127, qcg = p >> 7;
    int h = qcg >> 1, d0 = (qcg & 1) * 8;
    const float* C = ctxS + h * 256;   // [d][e]
    float m[8] = {0.f, 0.f, 0.f, 0.f, 0.f, 0.f, 0.f, 0.f};
#pragma unroll 4
    for (int e = 0; e < 16; ++e) {
      float wv = Wo[(size_t)(h * 16 + e) * 128 + oc];
#pragma unroll
      for (int i = 0; i < 8; ++i) m[i] += C[(d0 + i) * 16 + e] * wv;
    }
    union { uint4 q; unsigned short u[8]; } oh, ol;
#pragma unroll
    for (int i = 0; i < 8; ++i) splitf(m[i], oh.u[i], ol.u[i]);
    int grp = (((oc >> 4) * 4 + (qcg >> 2)) * 64) + (qcg & 3) * 16 + (oc & 15);
    *(uint4*)&mh[grp * 8] = oh.q;
    *(uint4*)&ml[grp * 8] = ol.q;
  }
  __syncthreads();                 // M ready in LDS

  floatx4 oacc[8];
#pragma unroll
  for (int i = 0; i < 8; ++i) oacc[i] = (floatx4){0.f, 0.f, 0.f, 0.f};

#pragma unroll
  for (int nt = 0; nt < 8; ++nt) {
#pragma unroll
    for (int ks = 0; ks < 4; ++ks) {
      int moff = ((nt * 4 + ks) * 64 + l) * 8;        // frag-major: lane-contiguous 16B
      short8 wbh = *(const short8*)&mh[moff];
      short8 wbl = *(const short8*)&ml[moff];
      oacc[nt] = MFMA(ah[ks], wbh, oacc[nt], 0, 0, 0);
      oacc[nt] = MFMA(al[ks], wbh, oacc[nt], 0, 0, 0);
      oacc[nt] = MFMA(ah[ks], wbl, oacc[nt], 0, 0, 0);
    }
  }

#pragma unroll
  for (int nt = 0; nt < 8; ++nt) {
    int oc = nt * 16 + lane16;
    float bb = boS[oc];
#pragma unroll
    for (int r = 0; r < 4; ++r) {
      int t = row0 + w * 16 + quad * 4 + r;
      out[(size_t)t * 128 + oc] = oacc[nt][r] + bb;
    }
  }
}

extern "C" void kernel_launch(void* const* d_in, const int* in_sizes, int n_in,
                              void* d_out, int out_size, void* d_ws, size_t ws_size,
                              hipStream_t stream) {
  const float* x  = (const float*)d_in[0];
  const float* Wq = (const float*)d_in[1];
  const float* bq = (const float*)d_in[2];
  const float* Wk = (const float*)d_in[3];
  const float* bk = (const float*)d_in[4];
  const float* Wv = (const float*)d_in[5];
  const float* bv = (const float*)d_in[6];
  const float* Wo = (const float*)d_in[7];
  const float* bo = (const float*)d_in[8];
  float* out = (float*)d_out;

  // ws: qws 16.78MB | WTh 96KB | WTl 96KB | ctx 64KB | ksum 4KB | RC 256KB | RS 256KB
  unsigned short* qws = (unsigned short*)d_ws;         // 65536*128 shorts
  unsigned short* WTh = qws + 8388608;                 // 3 x 16384
  unsigned short* WTl = WTh + 49152;
  float* ctx  = (float*)(WTl + 49152);                 // 16384 f
  float* ksum = ctx + 16384;                           // 1024 f
  float* RC = ksum + 1024;                             // 65536 f
  float* RS = RC + 65536;                              // 65536 f

  k_prep<<<348, 256, 0, stream>>>(Wq, Wk, Wv, WTh, WTl, ctx, RC, RS);
  k_qkv<<<512, 512, 0, stream>>>(x, WTh, WTl, bq, bk, bv, RC, RS, ctx, ksum, qws);
  k_zout<<<512, 512, 0, stream>>>(qws, Wo, ctx, bo, ksum, out);
}

// Round 13
// 153.878 us; speedup vs baseline: 1.0945x; 1.0008x over previous
//
#include <hip/hip_runtime.h>
#include <hip/hip_bf16.h>

// LightningAttention MI355X — round 21.
// R20 (2-tile pipeline, 154.0us) + ctx/ksum atomic MERGE across the block's 2 tiles:
//   carry c_acc (MFMA C-operand) and s_acc across tile1's GEMM; issue ONE set of
//   atomics per block (epi1) instead of two. Halves ctx RMW count 2.1M -> 1.05M
//   (16K -> 8K serialized RMWs per ctx cache line at the TCC). Cost: ~5 VGPRs.
//   Signature: k_qkv WRITE_SIZE 25088 -> ~20700 KB (pinned all session until now).
// k_prep / k_zout identical to R20. 3 dispatches.
// B=8 T=8192 DM=128 H=8 Dh=16. Split-bf16 (hi+lo) on all MFMA surfaces except q' (bf16).

typedef __attribute__((ext_vector_type(8))) short short8;   // 8 bf16 (MFMA A/B frag)
typedef __attribute__((ext_vector_type(4))) float floatx4;  // MFMA C/D frag

#define DEV __device__ __forceinline__
#define MFMA __builtin_amdgcn_mfma_f32_16x16x32_bf16

#define XPAD 136   // x-tile row stride in shorts (17x16B slots)

DEV unsigned short bfh(float f) {
  unsigned int x = __float_as_uint(f);
  x += 0x7fffu + ((x >> 16) & 1u);     // RNE
  return (unsigned short)(x >> 16);
}
DEV float bfdec(unsigned short u) { return __uint_as_float(((unsigned int)u) << 16); }
DEV void splitf(float f, unsigned short& h, unsigned short& l) {
  h = bfh(f);
  l = bfh(f - bfdec(h));
}
DEV void split8(const float* p, short8& h8, short8& l8) {
  float4 a = *(const float4*)p;
  float4 b = *(const float4*)(p + 4);
  float v[8] = {a.x, a.y, a.z, a.w, b.x, b.y, b.z, b.w};
  union { short8 s; unsigned short u[8]; } H, L;
#pragma unroll
  for (int i = 0; i < 8; ++i) splitf(v[i], H.u[i], L.u[i]);
  h8 = H.s; l8 = L.s;
}

// Register transpose (verified R5-R7): C-layout tile val(n=lane16, m=mt*16+quad*4+r),
// rows m0/m1 -> split frag F[lane16][k=quad*8+j] over the 32-wide m-window.
DEV void xpose_frag(floatx4 m0, floatx4 m1, int lane16, int quad,
                    short8& hi, short8& lo) {
  union { short8 s; unsigned short u[8]; } H, L;
#pragma unroll
  for (int j = 0; j < 8; ++j) {
    int srcLane = lane16 + (((quad & 1) * 2 + (j >> 2)) << 4);
    float vA = __shfl(m0[j & 3], srcLane, 64);
    float vB = __shfl(m1[j & 3], srcLane, 64);
    float v = (quad < 2) ? vA : vB;
    splitf(v, H.u[j], L.u[j]);
  }
  hi = H.s; lo = L.s;
}

// async 16B global->LDS (per-lane gsrc; LDS dest must be wave-uniform base + lane*16)
DEV void async16(const void* g, void* l) {
  __builtin_amdgcn_global_load_lds(
      (const __attribute__((address_space(1))) unsigned int*)g,
      (__attribute__((address_space(3))) unsigned int*)l, 16, 0, 0);
}

// One 64-row GEMM tile: acc[mat][mt] = x_tile @ {Wq,Wk,Wv} (split-bf16, 48 MFMAs)
DEV void gemm_tile(const unsigned short* __restrict__ xh, const unsigned short* __restrict__ xl,
                   const unsigned short* __restrict__ WTh, const unsigned short* __restrict__ WTl,
                   const size_t* wbase, int lane16, int quad, floatx4 (&acc)[3][4]) {
#pragma unroll
  for (int i = 0; i < 3; ++i)
#pragma unroll
    for (int j = 0; j < 4; ++j) acc[i][j] = (floatx4){0.f, 0.f, 0.f, 0.f};

  short8 wh[2][3], wl[2][3];       // double-buffered weight frags
#pragma unroll
  for (int mat = 0; mat < 3; ++mat) {
    wh[0][mat] = *(const short8*)(WTh + wbase[mat]);
    wl[0][mat] = *(const short8*)(WTl + wbase[mat]);
  }
#pragma unroll
  for (int ks = 0; ks < 4; ++ks) {
    const int cur = ks & 1, nxt = cur ^ 1;
    if (ks < 3) {
#pragma unroll
      for (int mat = 0; mat < 3; ++mat) {
        wh[nxt][mat] = *(const short8*)(WTh + wbase[mat] + (ks + 1) * 32);
        wl[nxt][mat] = *(const short8*)(WTl + wbase[mat] + (ks + 1) * 32);
      }
    }
    short8 afh[4], afl[4];
#pragma unroll
    for (int mt = 0; mt < 4; ++mt) {
      int off = (mt * 16 + lane16) * XPAD + ks * 32 + quad * 8;
      afh[mt] = *(const short8*)&xh[off];
      afl[mt] = *(const short8*)&xl[off];
    }
#pragma unroll
    for (int mat = 0; mat < 3; ++mat) {
#pragma unroll
      for (int mt = 0; mt < 4; ++mt) {
        acc[mat][mt] = MFMA(afh[mt], wh[cur][mat], acc[mat][mt], 0, 0, 0);
        acc[mat][mt] = MFMA(afl[mt], wh[cur][mat], acc[mat][mt], 0, 0, 0);
        acc[mat][mt] = MFMA(afh[mt], wl[cur][mat], acc[mat][mt], 0, 0, 0);
      }
    }
  }
}

// Epilogue for one tile. Accumulates ksum into s_acc and ctx into c_acc (MFMA C-op);
// FINAL=true issues the single per-block set of atomics (early, so the drain overlaps
// the q-side work that follows).
template <bool FINAL>
DEV void epilogue_tile(floatx4 (&acc)[3][4], const float (*rc)[9], const float (*rs)[9],
                       int roff, int trow0, int b, int w, int lane16, int quad, int l,
                       const float* bq, const float* bk, const float* bv,
                       float* __restrict__ ctx, float* __restrict__ ksum,
                       unsigned short* __restrict__ qws,
                       float& s_acc, floatx4& c_acc) {
  {  // bias
    int col = w * 16 + lane16;
    float bias[3] = {bq[col], bk[col], bv[col]};
#pragma unroll
    for (int mat = 0; mat < 3; ++mat)
#pragma unroll
      for (int mt = 0; mt < 4; ++mt)
#pragma unroll
        for (int r = 0; r < 4; ++r) acc[mat][mt][r] += bias[mat];
  }
  const int d = lane16, jj = d & 7;

  // rope + elu+1 on K first (feeds ksum/ctx)
#pragma unroll
  for (int mt = 0; mt < 4; ++mt) {
#pragma unroll
    for (int r = 0; r < 4; ++r) {
      int tl = roff + mt * 16 + quad * 4 + r;
      float cc = rc[tl][jj], ss = rs[tl][jj];
      float v = acc[1][mt][r];
      float p = __shfl_xor(v, 8);          // pair (d, d+8)
      float nv = (d < 8) ? (v * cc - p * ss) : (p * ss + v * cc);
      acc[1][mt][r] = (nv > 0.f) ? (nv + 1.f) : __expf(nv);
    }
  }
  // ksum raw per-lane accumulation (reduce + atomic only on FINAL)
#pragma unroll
  for (int mt = 0; mt < 4; ++mt)
#pragma unroll
    for (int r = 0; r < 4; ++r) s_acc += acc[1][mt][r];
  if (FINAL) {
    float s = s_acc;
    s += __shfl_xor(s, 16);
    s += __shfl_xor(s, 32);
    if (l < 16) atomicAdd(&ksum[(b * 8 + w) * 16 + lane16], s);
  }
  // ctx accumulation via MFMA C-operand (atomics only on FINAL)
#pragma unroll
  for (int ks2 = 0; ks2 < 2; ++ks2) {
    short8 kh, kl, vh, vl;
    xpose_frag(acc[1][ks2 * 2], acc[1][ks2 * 2 + 1], lane16, quad, kh, kl);
    xpose_frag(acc[2][ks2 * 2], acc[2][ks2 * 2 + 1], lane16, quad, vh, vl);
    c_acc = MFMA(kh, vh, c_acc, 0, 0, 0);
    c_acc = MFMA(kl, vh, c_acc, 0, 0, 0);
    c_acc = MFMA(kh, vl, c_acc, 0, 0, 0);
  }
  if (FINAL) {
#pragma unroll
    for (int r = 0; r < 4; ++r)
      atomicAdd(&ctx[((size_t)(b * 8 + w) * 16 + quad * 4 + r) * 16 + lane16], c_acc[r]);
  }
  // rope + elu+1 on Q + q' stores (atomic drain overlaps this on FINAL; on tile 0 it
  // drains under tile 1's GEMM)
#pragma unroll
  for (int mt = 0; mt < 4; ++mt) {
#pragma unroll
    for (int r = 0; r < 4; ++r) {
      int tl = roff + mt * 16 + quad * 4 + r;
      float cc = rc[tl][jj], ss = rs[tl][jj];
      float v = acc[0][mt][r];
      float p = __shfl_xor(v, 8);          // pair (d, d+8)
      float nv = (d < 8) ? (v * cc - p * ss) : (p * ss + v * cc);
      acc[0][mt][r] = (nv > 0.f) ? (nv + 1.f) : __expf(nv);
    }
  }
#pragma unroll
  for (int mt = 0; mt < 4; ++mt)
#pragma unroll
    for (int r = 0; r < 4; ++r)
      qws[(size_t)(trow0 + mt * 16 + quad * 4 + r) * 128 + w * 16 + lane16] =
          bfh(acc[0][mt][r]);
}

// ---------------- k_prep: Wq/Wk/Wv split-transpose + zero ctx/ksum + rope table ----------------
__global__ void k_prep(const float* __restrict__ Wq, const float* __restrict__ Wk,
                       const float* __restrict__ Wv,
                       unsigned short* __restrict__ WTh, unsigned short* __restrict__ WTl,
                       float* __restrict__ ctxz,
                       float* __restrict__ RC, float* __restrict__ RS) {
  int gid = blockIdx.x * 256 + threadIdx.x;
  if (gid < 6144) {               // 3 mats x 128 n x 16 k-groups of 8
    int mat = gid >> 11, r = gid & 2047, n = r >> 4, k0 = (r & 15) * 8;
    const float* W = (mat == 0) ? Wq : (mat == 1) ? Wk : Wv;
    union { uint4 q; unsigned short u[8]; } oh, ol;
#pragma unroll
    for (int i = 0; i < 8; ++i) splitf(W[(size_t)(k0 + i) * 128 + n], oh.u[i], ol.u[i]);
    *(uint4*)&WTh[mat * 16384 + n * 128 + k0] = oh.q;
    *(uint4*)&WTl[mat * 16384 + n * 128 + k0] = ol.q;
  } else if (gid < 6144 + 17408) {
    ctxz[gid - 6144] = 0.0f;      // ctx (16384) + ksum (1024)
  } else if (gid < 23552 + 65536) {
    int idx = gid - 23552;        // t*8 + j, T=8192
    int t = idx >> 3, j = idx & 7;
    float invf = 1.0f / powf(10000.0f, (float)j * 0.125f);
    float s, c;
    sincosf((float)t * invf, &s, &c);
    RC[idx] = c; RS[idx] = s;     // bit-identical to the old per-block computation
  }
}

// ---------------- kernel 1: qkv, 2-tile pipelined, merged atomics. 512 blocks x 512 thr ----------------
__global__ __launch_bounds__(512) void k_qkv(
    const float* __restrict__ x,
    const unsigned short* __restrict__ WTh, const unsigned short* __restrict__ WTl,
    const float* __restrict__ bq, const float* __restrict__ bk, const float* __restrict__ bv,
    const float* __restrict__ RC, const float* __restrict__ RS,
    float* __restrict__ ctx, float* __restrict__ ksum,
    unsigned short* __restrict__ qws) {
  __shared__ unsigned short xh[2][64 * XPAD], xl[2][64 * XPAD];  // 69632B dbuf
  __shared__ float rc[128][9], rs[128][9];                        // 9216B
  const int tid = threadIdx.x;
  const int row0 = blockIdx.x * 128;
  const int b = row0 >> 13;     // 128 | 8192 -> constant across both tiles
  const int t0 = row0 & 8191;

  {  // rope table for all 128 rows: 512 threads x 2
#pragma unroll
    for (int it = 0; it < 2; ++it) {
      int ii = it * 512 + tid;
      int r = ii >> 3, j = ii & 7;
      int idx = (t0 + r) * 8 + j;
      rc[r][j] = RC[idx];
      rs[r][j] = RS[idx];
    }
  }
  {  // stage tile 0
    int r = tid >> 3, cg = (tid & 7) * 16;
    const float* xp = x + (size_t)(row0 + r) * 128 + cg;
    short8 h0, l0, h1, l1;
    split8(xp, h0, l0);
    split8(xp + 8, h1, l1);
    *(short8*)&xh[0][r * XPAD + cg] = h0;
    *(short8*)&xh[0][r * XPAD + cg + 8] = h1;
    *(short8*)&xl[0][r * XPAD + cg] = l0;
    *(short8*)&xl[0][r * XPAD + cg + 8] = l1;
  }
  __syncthreads();

  const int l = tid & 63, w = tid >> 6;       // wave w owns head w
  const int lane16 = l & 15, quad = l >> 4;

  size_t wbase[3];
#pragma unroll
  for (int mat = 0; mat < 3; ++mat)
    wbase[mat] = (size_t)mat * 16384 + (size_t)(w * 16 + lane16) * 128 + quad * 8;

  floatx4 acc[3][4];               // 48 AGPRs
  float s_acc = 0.f;               // ksum carry across tiles
  floatx4 c_acc = (floatx4){0.f, 0.f, 0.f, 0.f};  // ctx carry across tiles

  // ---- tile 0 GEMM ----
  gemm_tile(xh[0], xl[0], WTh, WTl, wbase, lane16, quad, acc);

  // ---- stage tile 1 (overlaps other block; split+write hidden by epi0 below) ----
  {
    int r = tid >> 3, cg = (tid & 7) * 16;
    const float* xp = x + (size_t)(row0 + 64 + r) * 128 + cg;
    short8 h0, l0, h1, l1;
    split8(xp, h0, l0);
    split8(xp + 8, h1, l1);
    *(short8*)&xh[1][r * XPAD + cg] = h0;
    *(short8*)&xh[1][r * XPAD + cg + 8] = h1;
    *(short8*)&xl[1][r * XPAD + cg] = l0;
    *(short8*)&xl[1][r * XPAD + cg + 8] = l1;
  }
  __syncthreads();

  // ---- tile 0 epilogue: accumulate only, NO atomics ----
  epilogue_tile<false>(acc, rc, rs, 0, row0, b, w, lane16, quad, l,
                       bq, bk, bv, ctx, ksum, qws, s_acc, c_acc);

  // ---- tile 1 GEMM + final epilogue (single per-block atomic set, issued early) ----
  gemm_tile(xh[1], xl[1], WTh, WTl, wbase, lane16, quad, acc);
  epilogue_tile<true>(acc, rc, rs, 64, row0 + 64, b, w, lane16, quad, l,
                      bq, bk, bv, ctx, ksum, qws, s_acc, c_acc);
}

// ---------------- kernel 2: out = (z .* q') @ (ctx_b @ Wo) + bo, M built in-block ----------------
// 512 blocks x 512 thr (8 waves); block = 128 rows, wave w = one 16-row m-tile.
__global__ __launch_bounds__(512) void k_zout(
    const unsigned short* __restrict__ qws,
    const float* __restrict__ Wo, const float* __restrict__ ctx,
    const float* __restrict__ bo, const float* __restrict__ ksum,
    float* __restrict__ out) {
  __shared__ __align__(16) unsigned char SM[74240];
  unsigned short* mh = (unsigned short*)SM;            // 16384 shorts (32KB)
  unsigned short* ml = (unsigned short*)(SM + 32768);  // 32KB
  float* ctxS = (float*)(SM + 65536);                  // 2048 f (8KB)
  float* boS  = (float*)(SM + 73728);                  // 128 f
  const int tid = threadIdx.x;
  const int row0 = blockIdx.x * 128;
  const int b = row0 >> 13;
  const int l = tid & 63, w = tid >> 6;
  const int lane16 = l & 15, quad = l >> 4;

  {  // async-stage ctx_b (8KB): wave w copies chunk w*1KB
    const char* gc = (const char*)(ctx + (size_t)b * 2048);
    int off = w * 1024 + l * 16;
    async16(gc + off, (char*)ctxS + off);
  }
  if (tid >= 128 && tid < 256) boS[tid - 128] = bo[tid - 128];

  // A-frags: q' from ws (frag-layout), z in-reg, scale+split — overlapped with staging
  short8 ah[4], al[4];
  {
    int trow = row0 + w * 16 + lane16;      // lane16 = t within the wave's 16-row strip
    const float* kg = ksum + b * 128;
#pragma unroll
    for (int ks = 0; ks < 4; ++ks) {
      union { short8 s8; unsigned short u[8]; } qq;
      qq.s8 = *(const short8*)&qws[(size_t)trow * 128 + ks * 32 + quad * 8];
      int kb = ks * 32 + quad * 8;
      float4 kf0 = *(const float4*)(kg + kb);
      float4 kf1 = *(const float4*)(kg + kb + 4);
      float kf[8] = {kf0.x, kf0.y, kf0.z, kf0.w, kf1.x, kf1.y, kf1.z, kf1.w};
      float s = 0.f;
#pragma unroll
      for (int j = 0; j < 8; ++j) s += bfdec(qq.u[j]) * kf[j];
      s += __shfl_xor(s, 16);        // combine the two 8-halves of the head
      float z = 1.0f / (s + 1e-6f);
      union { short8 s8; unsigned short u[8]; } H, L;
#pragma unroll
      for (int j = 0; j < 8; ++j) splitf(bfdec(qq.u[j]) * z, H.u[j], L.u[j]);
      ah[ks] = H.s8;
      al[ks] = L.s8;
    }
  }
  __syncthreads();                 // ctx_b staged (A-frag prologue hidden under it)

  // build M = ctx_b @ Wo into mh/ml (frag-major permuted layout; e-loop order = k_mprep)
#pragma unroll
  for (int pp = 0; pp < 4; ++pp) {
    int p = pp * 512 + tid;        // 2048 (oc,qcg) pairs
    int oc = p & 127, qcg = p >> 7;
    int h = qcg >> 1, d0 = (qcg & 1) * 8;
    const float* C = ctxS + h * 256;   // [d][e]
    float m[8] = {0.f, 0.f, 0.f, 0.f, 0.f, 0.f, 0.f, 0.f};
#pragma unroll 4
    for (int e = 0; e < 16; ++e) {
      float wv = Wo[(size_t)(h * 16 + e) * 128 + oc];
#pragma unroll
      for (int i = 0; i < 8; ++i) m[i] += C[(d0 + i) * 16 + e] * wv;
    }
    union { uint4 q; unsigned short u[8]; } oh, ol;
#pragma unroll
    for (int i = 0; i < 8; ++i) splitf(m[i], oh.u[i], ol.u[i]);
    int grp = (((oc >> 4) * 4 + (qcg >> 2)) * 64) + (qcg & 3) * 16 + (oc & 15);
    *(uint4*)&mh[grp * 8] = oh.q;
    *(uint4*)&ml[grp * 8] = ol.q;
  }
  __syncthreads();                 // M ready in LDS

  floatx4 oacc[8];
#pragma unroll
  for (int i = 0; i < 8; ++i) oacc[i] = (floatx4){0.f, 0.f, 0.f, 0.f};

#pragma unroll
  for (int nt = 0; nt < 8; ++nt) {
#pragma unroll
    for (int ks = 0; ks < 4; ++ks) {
      int moff = ((nt * 4 + ks) * 64 + l) * 8;        // frag-major: lane-contiguous 16B
      short8 wbh = *(const short8*)&mh[moff];
      short8 wbl = *(const short8*)&ml[moff];
      oacc[nt] = MFMA(ah[ks], wbh, oacc[nt], 0, 0, 0);
      oacc[nt] = MFMA(al[ks], wbh, oacc[nt], 0, 0, 0);
      oacc[nt] = MFMA(ah[ks], wbl, oacc[nt], 0, 0, 0);
    }
  }

#pragma unroll
  for (int nt = 0; nt < 8; ++nt) {
    int oc = nt * 16 + lane16;
    float bb = boS[oc];
#pragma unroll
    for (int r = 0; r < 4; ++r) {
      int t = row0 + w * 16 + quad * 4 + r;
      out[(size_t)t * 128 + oc] = oacc[nt][r] + bb;
    }
  }
}

extern "C" void kernel_launch(void* const* d_in, const int* in_sizes, int n_in,
                              void* d_out, int out_size, void* d_ws, size_t ws_size,
                              hipStream_t stream) {
  const float* x  = (const float*)d_in[0];
  const float* Wq = (const float*)d_in[1];
  const float* bq = (const float*)d_in[2];
  const float* Wk = (const float*)d_in[3];
  const float* bk = (const float*)d_in[4];
  const float* Wv = (const float*)d_in[5];
  const float* bv = (const float*)d_in[6];
  const float* Wo = (const float*)d_in[7];
  const float* bo = (const float*)d_in[8];
  float* out = (float*)d_out;

  // ws: qws 16.78MB | WTh 96KB | WTl 96KB | ctx 64KB | ksum 4KB | RC 256KB | RS 256KB
  unsigned short* qws = (unsigned short*)d_ws;         // 65536*128 shorts
  unsigned short* WTh = qws + 8388608;                 // 3 x 16384
  unsigned short* WTl = WTh + 49152;
  float* ctx  = (float*)(WTl + 49152);                 // 16384 f
  float* ksum = ctx + 16384;                           // 1024 f
  float* RC = ksum + 1024;                             // 65536 f
  float* RS = RC + 65536;                              // 65536 f

  k_prep<<<348, 256, 0, stream>>>(Wq, Wk, Wv, WTh, WTl, ctx, RC, RS);
  k_qkv<<<512, 512, 0, stream>>>(x, WTh, WTl, bq, bk, bv, RC, RS, ctx, ksum, qws);
  k_zout<<<512, 512, 0, stream>>>(qws, Wo, ctx, bo, ksum, out);
}